// Round 1
// baseline (1096.545 us; speedup 1.0000x reference)
//
#include <hip/hip_runtime.h>

// GIN-2layer + pool + classifier for MI355X.
// Structure:
//   CSR build (hist/scan/scatter)  -- reused by both GIN layers
//   y1 = x @ W1                    -- GEMM (linearity: aggregate AFTER matmul, 4x less gather)
//   h1 = y1 + b1 + gather-sum(y1)  -- + BN batch-stat partials
//   BN1 finalize -> scale/shift
//   y2 = relu(relu(BN1(h1)) @ W2 + b2) @ W3
//   h2pre = y2 + b3 + gather-sum(y2) -- + BN2 partials
//   BN2 finalize
//   h2 = relu(BN2(h2pre)) @ W4 + b4
//   pool: per-graph wave (batch sorted -> contiguous ranges), mean||max -> z[G,64]
//   out = relu(z @ Wc1 + bc1) @ Wc2 + bc2

#define H 32
#define FIN 128
#define AGG_BLOCKS 2048

__device__ __forceinline__ int lower_bound_i(const int* __restrict__ a, int n, int key) {
  int lo = 0, hi = n;
  while (lo < hi) { int mid = (lo + hi) >> 1; if (a[mid] < key) lo = mid + 1; else hi = mid; }
  return lo;
}

__global__ void k_hist(const int* __restrict__ dst, int E, int* __restrict__ counts) {
  int i = blockIdx.x * blockDim.x + threadIdx.x;
  if (i < E) atomicAdd(&counts[dst[i]], 1);
}

__global__ __launch_bounds__(1024) void k_scan(const int* __restrict__ counts, int N,
                                               int* __restrict__ row_ptr, int* __restrict__ cursor) {
  __shared__ int part[1024];
  int t = threadIdx.x;
  int CH = (N + 1023) >> 10;
  int lo = t * CH, hi = min(lo + CH, N);
  int s = 0;
  for (int i = lo; i < hi; ++i) s += counts[i];
  part[t] = s;
  __syncthreads();
  for (int d = 1; d < 1024; d <<= 1) {
    int v = (t >= d) ? part[t - d] : 0;
    __syncthreads();
    part[t] += v;
    __syncthreads();
  }
  int run = (t == 0) ? 0 : part[t - 1];
  for (int i = lo; i < hi; ++i) {
    row_ptr[i] = run; cursor[i] = run; run += counts[i];
  }
  if (t == 1023) row_ptr[N] = part[1023];
}

__global__ void k_scatter(const int* __restrict__ src, const int* __restrict__ dst, int E,
                          int* __restrict__ cursor, int* __restrict__ csr) {
  int i = blockIdx.x * blockDim.x + threadIdx.x;
  if (i < E) {
    int p = atomicAdd(&cursor[dst[i]], 1);
    csr[p] = src[i];
  }
}

// y[N,32] = x[N,128] @ W[128,32].  128 nodes/block, thread tile 4 nodes x 4 cols.
__global__ __launch_bounds__(256) void k_gemm1(const float* __restrict__ x, const float* __restrict__ W,
                                               float* __restrict__ y, int N) {
  __shared__ __align__(16) float ws[FIN * H];   // 16 KB, [k][c]
  __shared__ __align__(16) float xs[128 * 33];  // k-chunk of 32 (+1 pad)
  int t = threadIdx.x;
  for (int i = t; i < FIN * H; i += 256) ws[i] = W[i];
  int nb = blockIdx.x * 128;
  int r0 = (t >> 3) * 4;   // 0..124
  int c0 = (t & 7) * 4;    // 0..28
  float acc[4][4] = {{0.f,0.f,0.f,0.f},{0.f,0.f,0.f,0.f},{0.f,0.f,0.f,0.f},{0.f,0.f,0.f,0.f}};
  for (int kb = 0; kb < FIN; kb += 32) {
    __syncthreads();
    for (int i = t; i < 1024; i += 256) {  // 1024 float4 = [128][32] chunk
      int n = i >> 3, k4 = (i & 7) * 4;
      float4 v = make_float4(0.f, 0.f, 0.f, 0.f);
      int gn = nb + n;
      if (gn < N) v = *(const float4*)&x[(size_t)gn * FIN + kb + k4];
      xs[n * 33 + k4 + 0] = v.x; xs[n * 33 + k4 + 1] = v.y;
      xs[n * 33 + k4 + 2] = v.z; xs[n * 33 + k4 + 3] = v.w;
    }
    __syncthreads();
#pragma unroll
    for (int k = 0; k < 32; ++k) {
      float4 wv = *(const float4*)&ws[(kb + k) * H + c0];
      float x0 = xs[(r0 + 0) * 33 + k];
      float x1 = xs[(r0 + 1) * 33 + k];
      float x2 = xs[(r0 + 2) * 33 + k];
      float x3 = xs[(r0 + 3) * 33 + k];
      acc[0][0] += x0 * wv.x; acc[0][1] += x0 * wv.y; acc[0][2] += x0 * wv.z; acc[0][3] += x0 * wv.w;
      acc[1][0] += x1 * wv.x; acc[1][1] += x1 * wv.y; acc[1][2] += x1 * wv.z; acc[1][3] += x1 * wv.w;
      acc[2][0] += x2 * wv.x; acc[2][1] += x2 * wv.y; acc[2][2] += x2 * wv.z; acc[2][3] += x2 * wv.w;
      acc[3][0] += x3 * wv.x; acc[3][1] += x3 * wv.y; acc[3][2] += x3 * wv.z; acc[3][3] += x3 * wv.w;
    }
  }
#pragma unroll
  for (int r = 0; r < 4; ++r) {
    int gn = nb + r0 + r;
    if (gn < N)
      *(float4*)&y[(size_t)gn * H + c0] = make_float4(acc[r][0], acc[r][1], acc[r][2], acc[r][3]);
  }
}

// hout[n] = y[n] + bias + sum_{j in in(n)} y[j];  also per-block BN partials (sum, sumsq).
// One wave per node: lane = epar(2) x channel(32). Coalesced 128B row gathers, no atomics.
__global__ __launch_bounds__(256) void k_agg(const float* __restrict__ y, const float* __restrict__ bias,
                                             const int* __restrict__ row_ptr, const int* __restrict__ csr,
                                             float* __restrict__ hout, float* __restrict__ bn_part, int N) {
  int wid = threadIdx.x >> 6, lane = threadIdx.x & 63;
  int c = lane & 31, ep = lane >> 5;
  float rsum = 0.f, rsq = 0.f;
  float bc = bias[c];
  int stride = gridDim.x * 4;
  for (int n = blockIdx.x * 4 + wid; n < N; n += stride) {
    int beg = row_ptr[n], end = row_ptr[n + 1];
    float acc = 0.f;
    for (int e = beg + ep; e < end; e += 2) {
      int j = csr[e];
      acc += y[(size_t)j * H + c];
    }
    acc += __shfl_xor(acc, 32, 64);
    float v = acc + y[(size_t)n * H + c] + bc;
    if (ep == 0) {
      hout[(size_t)n * H + c] = v;
      rsum += v; rsq += v * v;
    }
  }
  __shared__ float bsum[4][H], bsq[4][H];
  if (ep == 0) { bsum[wid][c] = rsum; bsq[wid][c] = rsq; }
  __syncthreads();
  if (threadIdx.x < H) {
    int cc = threadIdx.x;
    bn_part[(size_t)blockIdx.x * 64 + cc]     = bsum[0][cc] + bsum[1][cc] + bsum[2][cc] + bsum[3][cc];
    bn_part[(size_t)blockIdx.x * 64 + H + cc] = bsq[0][cc] + bsq[1][cc] + bsq[2][cc] + bsq[3][cc];
  }
}

__global__ __launch_bounds__(256) void k_bnfin(const float* __restrict__ part, int nblk,
                                               const float* __restrict__ gma, const float* __restrict__ bet,
                                               float* __restrict__ sc, float invN) {
  int t = threadIdx.x;
  int col = t & 63, q = t >> 6;   // 4 slices
  int per = nblk >> 2;
  float s = 0.f;
  for (int r = q * per; r < (q + 1) * per; ++r) s += part[(size_t)r * 64 + col];
  __shared__ float red[4][64];
  __shared__ float tot[64];
  red[q][col] = s;
  __syncthreads();
  if (t < 64) tot[t] = red[0][t] + red[1][t] + red[2][t] + red[3][t];
  __syncthreads();
  if (t < H) {
    float mean = tot[t] * invN;
    float var = tot[H + t] * invN - mean * mean;
    float scale = gma[t] * rsqrtf(var + 1e-5f);
    sc[t] = scale;
    sc[H + t] = bet[t] - mean * scale;
  }
}

// y2 = relu(relu(BN1(h1)) @ W2 + b2) @ W3 ; thread per node, W in LDS (uniform broadcast reads).
__global__ __launch_bounds__(256) void k_mlp1(const float* __restrict__ h1, const float* __restrict__ sc,
                                              const float* __restrict__ W2, const float* __restrict__ b2,
                                              const float* __restrict__ W3, float* __restrict__ y2, int N) {
  __shared__ __align__(16) float ws2[H * H], ws3[H * H];
  __shared__ float scale_s[H], shift_s[H], b2s[H];
  int t = threadIdx.x;
  for (int i = t; i < H * H; i += 256) { ws2[i] = W2[i]; ws3[i] = W3[i]; }
  if (t < H) { scale_s[t] = sc[t]; shift_s[t] = sc[H + t]; b2s[t] = b2[t]; }
  __syncthreads();
  int n = blockIdx.x * 256 + t;
  if (n >= N) return;
  float a[H], u[H], o[H];
  const float4* hin = (const float4*)&h1[(size_t)n * H];
#pragma unroll
  for (int q = 0; q < H / 4; ++q) {
    float4 v = hin[q];
    a[q * 4 + 0] = fmaxf(v.x * scale_s[q * 4 + 0] + shift_s[q * 4 + 0], 0.f);
    a[q * 4 + 1] = fmaxf(v.y * scale_s[q * 4 + 1] + shift_s[q * 4 + 1], 0.f);
    a[q * 4 + 2] = fmaxf(v.z * scale_s[q * 4 + 2] + shift_s[q * 4 + 2], 0.f);
    a[q * 4 + 3] = fmaxf(v.w * scale_s[q * 4 + 3] + shift_s[q * 4 + 3], 0.f);
  }
#pragma unroll
  for (int c = 0; c < H; ++c) u[c] = b2s[c];
#pragma unroll
  for (int k = 0; k < H; ++k) {
    float av = a[k];
    const float4* wr = (const float4*)&ws2[k * H];
#pragma unroll
    for (int q = 0; q < H / 4; ++q) {
      float4 wv = wr[q];
      u[q * 4 + 0] += av * wv.x; u[q * 4 + 1] += av * wv.y;
      u[q * 4 + 2] += av * wv.z; u[q * 4 + 3] += av * wv.w;
    }
  }
#pragma unroll
  for (int c = 0; c < H; ++c) { u[c] = fmaxf(u[c], 0.f); o[c] = 0.f; }
#pragma unroll
  for (int k = 0; k < H; ++k) {
    float av = u[k];
    const float4* wr = (const float4*)&ws3[k * H];
#pragma unroll
    for (int q = 0; q < H / 4; ++q) {
      float4 wv = wr[q];
      o[q * 4 + 0] += av * wv.x; o[q * 4 + 1] += av * wv.y;
      o[q * 4 + 2] += av * wv.z; o[q * 4 + 3] += av * wv.w;
    }
  }
  float4* yo = (float4*)&y2[(size_t)n * H];
#pragma unroll
  for (int q = 0; q < H / 4; ++q)
    yo[q] = make_float4(o[q * 4 + 0], o[q * 4 + 1], o[q * 4 + 2], o[q * 4 + 3]);
}

// h2 = relu(BN2(h2pre)) @ W4 + b4   (no trailing relu)
__global__ __launch_bounds__(256) void k_mlp2(const float* __restrict__ hpre, const float* __restrict__ sc,
                                              const float* __restrict__ W4, const float* __restrict__ b4,
                                              float* __restrict__ h2, int N) {
  __shared__ __align__(16) float ws4[H * H];
  __shared__ float scale_s[H], shift_s[H], b4s[H];
  int t = threadIdx.x;
  for (int i = t; i < H * H; i += 256) ws4[i] = W4[i];
  if (t < H) { scale_s[t] = sc[t]; shift_s[t] = sc[H + t]; b4s[t] = b4[t]; }
  __syncthreads();
  int n = blockIdx.x * 256 + t;
  if (n >= N) return;
  float a[H], o[H];
  const float4* hin = (const float4*)&hpre[(size_t)n * H];
#pragma unroll
  for (int q = 0; q < H / 4; ++q) {
    float4 v = hin[q];
    a[q * 4 + 0] = fmaxf(v.x * scale_s[q * 4 + 0] + shift_s[q * 4 + 0], 0.f);
    a[q * 4 + 1] = fmaxf(v.y * scale_s[q * 4 + 1] + shift_s[q * 4 + 1], 0.f);
    a[q * 4 + 2] = fmaxf(v.z * scale_s[q * 4 + 2] + shift_s[q * 4 + 2], 0.f);
    a[q * 4 + 3] = fmaxf(v.w * scale_s[q * 4 + 3] + shift_s[q * 4 + 3], 0.f);
  }
#pragma unroll
  for (int c = 0; c < H; ++c) o[c] = b4s[c];
#pragma unroll
  for (int k = 0; k < H; ++k) {
    float av = a[k];
    const float4* wr = (const float4*)&ws4[k * H];
#pragma unroll
    for (int q = 0; q < H / 4; ++q) {
      float4 wv = wr[q];
      o[q * 4 + 0] += av * wv.x; o[q * 4 + 1] += av * wv.y;
      o[q * 4 + 2] += av * wv.z; o[q * 4 + 3] += av * wv.w;
    }
  }
  float4* ho = (float4*)&h2[(size_t)n * H];
#pragma unroll
  for (int q = 0; q < H / 4; ++q)
    ho[q] = make_float4(o[q * 4 + 0], o[q * 4 + 1], o[q * 4 + 2], o[q * 4 + 3]);
}

// batch is sorted: graph g owns node range [lb(g), lb(g+1)). Wave per graph, mean||max -> z[G,64].
__global__ __launch_bounds__(256) void k_pool(const float* __restrict__ h2, const int* __restrict__ batch,
                                              int N, int G, float* __restrict__ z) {
  int wid = threadIdx.x >> 6, lane = threadIdx.x & 63;
  int g = blockIdx.x * 4 + wid;
  if (g >= G) return;
  int beg = lower_bound_i(batch, N, g);
  int end = lower_bound_i(batch, N, g + 1);
  int c = lane & 31, ep = lane >> 5;
  float s = 0.f, m = -3.402823466e38f;
  for (int i = beg + ep; i < end; i += 2) {
    float v = h2[(size_t)i * H + c];
    s += v; m = fmaxf(m, v);
  }
  s += __shfl_xor(s, 32, 64);
  m = fmaxf(m, __shfl_xor(m, 32, 64));
  if (ep == 0) {
    int cnt = end - beg;
    z[(size_t)g * 64 + c]     = (cnt > 0) ? s / (float)cnt : 0.f;
    z[(size_t)g * 64 + H + c] = (cnt > 0) ? m : 0.f;
  }
}

// out = relu(z @ Wc1 + bc1) @ Wc2 + bc2 ; thread per graph.
__global__ __launch_bounds__(256) void k_cls(const float* __restrict__ z, const float* __restrict__ Wc1,
                                             const float* __restrict__ bc1, const float* __restrict__ Wc2,
                                             const float* __restrict__ bc2, float* __restrict__ out, int G) {
  __shared__ __align__(16) float w1s[64 * H];
  __shared__ float w2s[H * 2], b1s[H], b2s[2];
  int t = threadIdx.x;
  for (int i = t; i < 64 * H; i += 256) w1s[i] = Wc1[i];
  if (t < H * 2) w2s[t] = Wc2[t];
  if (t < H) b1s[t] = bc1[t];
  if (t < 2) b2s[t] = bc2[t];
  __syncthreads();
  int g = blockIdx.x * 256 + t;
  if (g >= G) return;
  float zr[64], u[H];
  const float4* zp = (const float4*)&z[(size_t)g * 64];
#pragma unroll
  for (int q = 0; q < 16; ++q) {
    float4 v = zp[q];
    zr[q * 4 + 0] = v.x; zr[q * 4 + 1] = v.y; zr[q * 4 + 2] = v.z; zr[q * 4 + 3] = v.w;
  }
#pragma unroll
  for (int c = 0; c < H; ++c) u[c] = b1s[c];
#pragma unroll
  for (int k = 0; k < 64; ++k) {
    float av = zr[k];
    const float4* wr = (const float4*)&w1s[k * H];
#pragma unroll
    for (int q = 0; q < H / 4; ++q) {
      float4 wv = wr[q];
      u[q * 4 + 0] += av * wv.x; u[q * 4 + 1] += av * wv.y;
      u[q * 4 + 2] += av * wv.z; u[q * 4 + 3] += av * wv.w;
    }
  }
  float o0 = b2s[0], o1 = b2s[1];
#pragma unroll
  for (int k = 0; k < H; ++k) {
    float uv = fmaxf(u[k], 0.f);
    o0 += uv * w2s[k * 2 + 0];
    o1 += uv * w2s[k * 2 + 1];
  }
  out[(size_t)g * 2 + 0] = o0;
  out[(size_t)g * 2 + 1] = o1;
}

extern "C" void kernel_launch(void* const* d_in, const int* in_sizes, int n_in,
                              void* d_out, int out_size, void* d_ws, size_t ws_size,
                              hipStream_t stream) {
  const float* x    = (const float*)d_in[0];
  const int*   eidx = (const int*)d_in[1];
  const int*   batch= (const int*)d_in[2];
  const float* W1 = (const float*)d_in[3];
  const float* b1 = (const float*)d_in[4];
  const float* g1 = (const float*)d_in[5];
  const float* be1= (const float*)d_in[6];
  const float* W2 = (const float*)d_in[7];
  const float* b2 = (const float*)d_in[8];
  const float* W3 = (const float*)d_in[9];
  const float* b3 = (const float*)d_in[10];
  const float* g2 = (const float*)d_in[11];
  const float* be2= (const float*)d_in[12];
  const float* W4 = (const float*)d_in[13];
  const float* b4 = (const float*)d_in[14];
  const float* Wc1= (const float*)d_in[15];
  const float* bc1= (const float*)d_in[16];
  const float* Wc2= (const float*)d_in[17];
  const float* bc2= (const float*)d_in[18];
  (void)n_in; (void)ws_size;

  int N = in_sizes[2];       // 100000
  int E = in_sizes[1] / 2;   // 1600000
  int G = out_size / 2;      // 1000
  const int* srcv = eidx;
  const int* dstv = eidx + E;

  char* w = (char*)d_ws;
  auto carve = [&](size_t bytes) { void* p = (void*)w; w += (bytes + 255) & ~(size_t)255; return p; };
  float* bufA   = (float*)carve((size_t)N * H * 4);      // y1 -> y2 -> h2
  float* bufB   = (float*)carve((size_t)N * H * 4);      // h1 -> h2pre
  int*   counts = (int*)carve((size_t)N * 4);
  int*   row_ptr= (int*)carve((size_t)(N + 1) * 4);
  int*   cursor = (int*)carve((size_t)N * 4);
  int*   csr    = (int*)carve((size_t)E * 4);
  float* bnp    = (float*)carve((size_t)AGG_BLOCKS * 64 * 4);
  float* sc1    = (float*)carve(64 * 4);
  float* sc2    = (float*)carve(64 * 4);
  float* z      = (float*)carve((size_t)G * 64 * 4);

  hipMemsetAsync(counts, 0, (size_t)N * 4, stream);
  k_hist<<<(E + 255) / 256, 256, 0, stream>>>(dstv, E, counts);
  k_scan<<<1, 1024, 0, stream>>>(counts, N, row_ptr, cursor);
  k_scatter<<<(E + 255) / 256, 256, 0, stream>>>(srcv, dstv, E, cursor, csr);
  k_gemm1<<<(N + 127) / 128, 256, 0, stream>>>(x, W1, bufA, N);
  k_agg<<<AGG_BLOCKS, 256, 0, stream>>>(bufA, b1, row_ptr, csr, bufB, bnp, N);
  k_bnfin<<<1, 256, 0, stream>>>(bnp, AGG_BLOCKS, g1, be1, sc1, 1.0f / (float)N);
  k_mlp1<<<(N + 255) / 256, 256, 0, stream>>>(bufB, sc1, W2, b2, W3, bufA, N);
  k_agg<<<AGG_BLOCKS, 256, 0, stream>>>(bufA, b3, row_ptr, csr, bufB, bnp, N);
  k_bnfin<<<1, 256, 0, stream>>>(bnp, AGG_BLOCKS, g2, be2, sc2, 1.0f / (float)N);
  k_mlp2<<<(N + 255) / 256, 256, 0, stream>>>(bufB, sc2, W4, b4, bufA, N);
  k_pool<<<(G + 3) / 4, 256, 0, stream>>>(bufA, batch, N, G, z);
  k_cls<<<(G + 255) / 256, 256, 0, stream>>>(z, Wc1, bc1, Wc2, bc2, (float*)d_out, G);
}

// Round 5
// 841.499 us; speedup vs baseline: 1.3031x; 1.3031x over previous
//
#include <hip/hip_runtime.h>

// GIN-2layer + pool + classifier for MI355X.
// R4 fix: k_agg's __shfl broadcast ran inside a lane-divergent loop; on CDNA
// ds_bpermute from an exec-inactive source lane is UNDEFINED (hit for odd
// degrees >= 33 -> garbage gather -> polluted BN stats; nondeterministic
// absmax 0.18/468). Now the broadcast loop is wave-uniform (all 64 lanes,
// uniform bound m, shfl at full convergence), accumulate predicated.
// Kept from R2: 3-phase parallel scan (replaces 232us 1-block scan).

#define H 32
#define FIN 128
#define AGG_BLOCKS 2048

#define SCAN_NB 256
#define SCAN_BT 256
#define SCAN_T  2   // elements per thread; NB*BT*T = 131072 >= N

__device__ __forceinline__ int lower_bound_i(const int* __restrict__ a, int n, int key) {
  int lo = 0, hi = n;
  while (lo < hi) { int mid = (lo + hi) >> 1; if (a[mid] < key) lo = mid + 1; else hi = mid; }
  return lo;
}

__global__ void k_hist(const int* __restrict__ dst, int E, int* __restrict__ counts) {
  int i = blockIdx.x * blockDim.x + threadIdx.x;
  if (i < E) atomicAdd(&counts[dst[i]], 1);
}

// ---- 3-phase scan ----
__global__ __launch_bounds__(SCAN_BT) void k_scan_part(const int* __restrict__ counts, int N,
                                                       int* __restrict__ blocksum) {
  int t = threadIdx.x, b = blockIdx.x;
  int base = (b * SCAN_BT + t) * SCAN_T;
  int s = 0;
#pragma unroll
  for (int i = 0; i < SCAN_T; ++i) {
    int idx = base + i;
    if (idx < N) s += counts[idx];
  }
  __shared__ int red[SCAN_BT];
  red[t] = s;
  __syncthreads();
  for (int d = SCAN_BT / 2; d > 0; d >>= 1) {
    if (t < d) red[t] += red[t + d];
    __syncthreads();
  }
  if (t == 0) blocksum[b] = red[0];
}

__global__ __launch_bounds__(SCAN_NB) void k_scan_top(const int* __restrict__ blocksum,
                                                      int* __restrict__ blockoff) {
  int t = threadIdx.x;
  __shared__ int sh[SCAN_NB];
  sh[t] = blocksum[t];
  __syncthreads();
  for (int d = 1; d < SCAN_NB; d <<= 1) {
    int v = (t >= d) ? sh[t - d] : 0;
    __syncthreads();
    sh[t] += v;
    __syncthreads();
  }
  blockoff[t] = (t == 0) ? 0 : sh[t - 1];
  if (t == SCAN_NB - 1) blockoff[SCAN_NB] = sh[t];
}

__global__ __launch_bounds__(SCAN_BT) void k_scan_out(const int* __restrict__ counts, int N,
                                                      const int* __restrict__ blockoff,
                                                      int* __restrict__ row_ptr, int* __restrict__ cursor) {
  int t = threadIdx.x, b = blockIdx.x;
  int base = (b * SCAN_BT + t) * SCAN_T;
  int v0 = (base < N) ? counts[base] : 0;
  int v1 = (base + 1 < N) ? counts[base + 1] : 0;
  __shared__ int sh[SCAN_BT];
  sh[t] = v0 + v1;
  __syncthreads();
  for (int d = 1; d < SCAN_BT; d <<= 1) {
    int v = (t >= d) ? sh[t - d] : 0;
    __syncthreads();
    sh[t] += v;
    __syncthreads();
  }
  int run = blockoff[b] + ((t == 0) ? 0 : sh[t - 1]);
  if (base < N)     { row_ptr[base] = run; cursor[base] = run; run += v0; }
  if (base + 1 < N) { row_ptr[base + 1] = run; cursor[base + 1] = run; }
  if (b == 0 && t == 0) row_ptr[N] = blockoff[SCAN_NB];
}

__global__ void k_scatter(const int* __restrict__ src, const int* __restrict__ dst, int E,
                          int* __restrict__ cursor, int* __restrict__ csr) {
  int i = blockIdx.x * blockDim.x + threadIdx.x;
  if (i < E) {
    int p = atomicAdd(&cursor[dst[i]], 1);
    csr[p] = src[i];
  }
}

// y[N,32] = x[N,128] @ W[128,32].  128 nodes/block, thread tile 4 nodes x 4 cols.
__global__ __launch_bounds__(256) void k_gemm1(const float* __restrict__ x, const float* __restrict__ W,
                                               float* __restrict__ y, int N) {
  __shared__ __align__(16) float ws[FIN * H];   // 16 KB, [k][c]
  __shared__ __align__(16) float xs[128 * 33];  // k-chunk of 32 (+1 pad)
  int t = threadIdx.x;
  for (int i = t; i < FIN * H; i += 256) ws[i] = W[i];
  int nb = blockIdx.x * 128;
  int r0 = (t >> 3) * 4;   // 0..124
  int c0 = (t & 7) * 4;    // 0..28
  float acc[4][4] = {{0.f,0.f,0.f,0.f},{0.f,0.f,0.f,0.f},{0.f,0.f,0.f,0.f},{0.f,0.f,0.f,0.f}};
  for (int kb = 0; kb < FIN; kb += 32) {
    __syncthreads();
    for (int i = t; i < 1024; i += 256) {  // 1024 float4 = [128][32] chunk
      int n = i >> 3, k4 = (i & 7) * 4;
      float4 v = make_float4(0.f, 0.f, 0.f, 0.f);
      int gn = nb + n;
      if (gn < N) v = *(const float4*)&x[(size_t)gn * FIN + kb + k4];
      xs[n * 33 + k4 + 0] = v.x; xs[n * 33 + k4 + 1] = v.y;
      xs[n * 33 + k4 + 2] = v.z; xs[n * 33 + k4 + 3] = v.w;
    }
    __syncthreads();
#pragma unroll
    for (int k = 0; k < 32; ++k) {
      float4 wv = *(const float4*)&ws[(kb + k) * H + c0];
      float x0 = xs[(r0 + 0) * 33 + k];
      float x1 = xs[(r0 + 1) * 33 + k];
      float x2 = xs[(r0 + 2) * 33 + k];
      float x3 = xs[(r0 + 3) * 33 + k];
      acc[0][0] += x0 * wv.x; acc[0][1] += x0 * wv.y; acc[0][2] += x0 * wv.z; acc[0][3] += x0 * wv.w;
      acc[1][0] += x1 * wv.x; acc[1][1] += x1 * wv.y; acc[1][2] += x1 * wv.z; acc[1][3] += x1 * wv.w;
      acc[2][0] += x2 * wv.x; acc[2][1] += x2 * wv.y; acc[2][2] += x2 * wv.z; acc[2][3] += x2 * wv.w;
      acc[3][0] += x3 * wv.x; acc[3][1] += x3 * wv.y; acc[3][2] += x3 * wv.z; acc[3][3] += x3 * wv.w;
    }
  }
#pragma unroll
  for (int r = 0; r < 4; ++r) {
    int gn = nb + r0 + r;
    if (gn < N)
      *(float4*)&y[(size_t)gn * H + c0] = make_float4(acc[r][0], acc[r][1], acc[r][2], acc[r][3]);
  }
}

// hout[n] = y[n] + bias + sum_{j in in(n)} y[j];  also per-block BN partials (sum, sumsq).
// One wave per node. csr indices loaded 64-wide coalesced, broadcast via shfl.
// The broadcast loop is WAVE-UNIFORM (bound m uniform, no divergence before the
// shfl) so every ds_bpermute source lane is active; odd-tail handled by
// clamping the source slot and predicating only the accumulate.
__global__ __launch_bounds__(256) void k_agg(const float* __restrict__ y, const float* __restrict__ bias,
                                             const int* __restrict__ row_ptr, const int* __restrict__ csr,
                                             float* __restrict__ hout, float* __restrict__ bn_part, int N) {
  int wid = threadIdx.x >> 6, lane = threadIdx.x & 63;
  int c = lane & 31, ep = lane >> 5;
  float rsum = 0.f, rsq = 0.f;
  float bc = bias[c];
  int stride = gridDim.x * 4;
  for (int n = blockIdx.x * 4 + wid; n < N; n += stride) {
    int beg = row_ptr[n], end = row_ptr[n + 1];
    float acc = 0.f;
    for (int b0 = beg; b0 < end; b0 += 64) {
      int m = end - b0; if (m > 64) m = 64;          // wave-uniform
      int idx = (lane < m) ? csr[b0 + lane] : 0;
      for (int r = 0; r < m; r += 2) {               // uniform trip count
        int s = r + ep;                              // may be == m when m odd, ep==1
        int j = __shfl(idx, (s < m) ? s : 0, 64);    // full-exec shfl, valid src
        float val = y[(size_t)j * H + c];
        if (s < m) acc += val;                       // predicated accumulate
      }
    }
    acc += __shfl_xor(acc, 32, 64);
    float v = acc + y[(size_t)n * H + c] + bc;
    if (ep == 0) {
      hout[(size_t)n * H + c] = v;
      rsum += v; rsq += v * v;
    }
  }
  __shared__ float bsum[4][H], bsq[4][H];
  if (ep == 0) { bsum[wid][c] = rsum; bsq[wid][c] = rsq; }
  __syncthreads();
  if (threadIdx.x < H) {
    int cc = threadIdx.x;
    bn_part[(size_t)blockIdx.x * 64 + cc]     = bsum[0][cc] + bsum[1][cc] + bsum[2][cc] + bsum[3][cc];
    bn_part[(size_t)blockIdx.x * 64 + H + cc] = bsq[0][cc] + bsq[1][cc] + bsq[2][cc] + bsq[3][cc];
  }
}

__global__ __launch_bounds__(256) void k_bnfin(const float* __restrict__ part, int nblk,
                                               const float* __restrict__ gma, const float* __restrict__ bet,
                                               float* __restrict__ sc, float invN) {
  int t = threadIdx.x;
  int col = t & 63, q = t >> 6;   // 4 slices
  int per = nblk >> 2;
  float s = 0.f;
  for (int r = q * per; r < (q + 1) * per; ++r) s += part[(size_t)r * 64 + col];
  __shared__ float red[4][64];
  __shared__ float tot[64];
  red[q][col] = s;
  __syncthreads();
  if (t < 64) tot[t] = red[0][t] + red[1][t] + red[2][t] + red[3][t];
  __syncthreads();
  if (t < H) {
    float mean = tot[t] * invN;
    float var = tot[H + t] * invN - mean * mean;
    float scale = gma[t] * rsqrtf(var + 1e-5f);
    sc[t] = scale;
    sc[H + t] = bet[t] - mean * scale;
  }
}

// y2 = relu(relu(BN1(h1)) @ W2 + b2) @ W3 ; thread per node, W in LDS (uniform broadcast reads).
__global__ __launch_bounds__(256) void k_mlp1(const float* __restrict__ h1, const float* __restrict__ sc,
                                              const float* __restrict__ W2, const float* __restrict__ b2,
                                              const float* __restrict__ W3, float* __restrict__ y2, int N) {
  __shared__ __align__(16) float ws2[H * H], ws3[H * H];
  __shared__ float scale_s[H], shift_s[H], b2s[H];
  int t = threadIdx.x;
  for (int i = t; i < H * H; i += 256) { ws2[i] = W2[i]; ws3[i] = W3[i]; }
  if (t < H) { scale_s[t] = sc[t]; shift_s[t] = sc[H + t]; b2s[t] = b2[t]; }
  __syncthreads();
  int n = blockIdx.x * 256 + t;
  if (n >= N) return;
  float a[H], u[H], o[H];
  const float4* hin = (const float4*)&h1[(size_t)n * H];
#pragma unroll
  for (int q = 0; q < H / 4; ++q) {
    float4 v = hin[q];
    a[q * 4 + 0] = fmaxf(v.x * scale_s[q * 4 + 0] + shift_s[q * 4 + 0], 0.f);
    a[q * 4 + 1] = fmaxf(v.y * scale_s[q * 4 + 1] + shift_s[q * 4 + 1], 0.f);
    a[q * 4 + 2] = fmaxf(v.z * scale_s[q * 4 + 2] + shift_s[q * 4 + 2], 0.f);
    a[q * 4 + 3] = fmaxf(v.w * scale_s[q * 4 + 3] + shift_s[q * 4 + 3], 0.f);
  }
#pragma unroll
  for (int c = 0; c < H; ++c) u[c] = b2s[c];
#pragma unroll
  for (int k = 0; k < H; ++k) {
    float av = a[k];
    const float4* wr = (const float4*)&ws2[k * H];
#pragma unroll
    for (int q = 0; q < H / 4; ++q) {
      float4 wv = wr[q];
      u[q * 4 + 0] += av * wv.x; u[q * 4 + 1] += av * wv.y;
      u[q * 4 + 2] += av * wv.z; u[q * 4 + 3] += av * wv.w;
    }
  }
#pragma unroll
  for (int c = 0; c < H; ++c) { u[c] = fmaxf(u[c], 0.f); o[c] = 0.f; }
#pragma unroll
  for (int k = 0; k < H; ++k) {
    float av = u[k];
    const float4* wr = (const float4*)&ws3[k * H];
#pragma unroll
    for (int q = 0; q < H / 4; ++q) {
      float4 wv = wr[q];
      o[q * 4 + 0] += av * wv.x; o[q * 4 + 1] += av * wv.y;
      o[q * 4 + 2] += av * wv.z; o[q * 4 + 3] += av * wv.w;
    }
  }
  float4* yo = (float4*)&y2[(size_t)n * H];
#pragma unroll
  for (int q = 0; q < H / 4; ++q)
    yo[q] = make_float4(o[q * 4 + 0], o[q * 4 + 1], o[q * 4 + 2], o[q * 4 + 3]);
}

// h2 = relu(BN2(h2pre)) @ W4 + b4   (no trailing relu)
__global__ __launch_bounds__(256) void k_mlp2(const float* __restrict__ hpre, const float* __restrict__ sc,
                                              const float* __restrict__ W4, const float* __restrict__ b4,
                                              float* __restrict__ h2, int N) {
  __shared__ __align__(16) float ws4[H * H];
  __shared__ float scale_s[H], shift_s[H], b4s[H];
  int t = threadIdx.x;
  for (int i = t; i < H * H; i += 256) ws4[i] = W4[i];
  if (t < H) { scale_s[t] = sc[t]; shift_s[t] = sc[H + t]; b4s[t] = b4[t]; }
  __syncthreads();
  int n = blockIdx.x * 256 + t;
  if (n >= N) return;
  float a[H], o[H];
  const float4* hin = (const float4*)&hpre[(size_t)n * H];
#pragma unroll
  for (int q = 0; q < H / 4; ++q) {
    float4 v = hin[q];
    a[q * 4 + 0] = fmaxf(v.x * scale_s[q * 4 + 0] + shift_s[q * 4 + 0], 0.f);
    a[q * 4 + 1] = fmaxf(v.y * scale_s[q * 4 + 1] + shift_s[q * 4 + 1], 0.f);
    a[q * 4 + 2] = fmaxf(v.z * scale_s[q * 4 + 2] + shift_s[q * 4 + 2], 0.f);
    a[q * 4 + 3] = fmaxf(v.w * scale_s[q * 4 + 3] + shift_s[q * 4 + 3], 0.f);
  }
#pragma unroll
  for (int c = 0; c < H; ++c) o[c] = b4s[c];
#pragma unroll
  for (int k = 0; k < H; ++k) {
    float av = a[k];
    const float4* wr = (const float4*)&ws4[k * H];
#pragma unroll
    for (int q = 0; q < H / 4; ++q) {
      float4 wv = wr[q];
      o[q * 4 + 0] += av * wv.x; o[q * 4 + 1] += av * wv.y;
      o[q * 4 + 2] += av * wv.z; o[q * 4 + 3] += av * wv.w;
    }
  }
  float4* ho = (float4*)&h2[(size_t)n * H];
#pragma unroll
  for (int q = 0; q < H / 4; ++q)
    ho[q] = make_float4(o[q * 4 + 0], o[q * 4 + 1], o[q * 4 + 2], o[q * 4 + 3]);
}

// batch is sorted: graph g owns node range [lb(g), lb(g+1)). Wave per graph, mean||max -> z[G,64].
__global__ __launch_bounds__(256) void k_pool(const float* __restrict__ h2, const int* __restrict__ batch,
                                              int N, int G, float* __restrict__ z) {
  int wid = threadIdx.x >> 6, lane = threadIdx.x & 63;
  int g = blockIdx.x * 4 + wid;
  if (g >= G) return;
  int beg = lower_bound_i(batch, N, g);
  int end = lower_bound_i(batch, N, g + 1);
  int c = lane & 31, ep = lane >> 5;
  float s = 0.f, m = -3.402823466e38f;
  for (int i = beg + ep; i < end; i += 2) {
    float v = h2[(size_t)i * H + c];
    s += v; m = fmaxf(m, v);
  }
  s += __shfl_xor(s, 32, 64);
  m = fmaxf(m, __shfl_xor(m, 32, 64));
  if (ep == 0) {
    int cnt = end - beg;
    z[(size_t)g * 64 + c]     = (cnt > 0) ? s / (float)cnt : 0.f;
    z[(size_t)g * 64 + H + c] = (cnt > 0) ? m : 0.f;
  }
}

// out = relu(z @ Wc1 + bc1) @ Wc2 + bc2 ; thread per graph.
__global__ __launch_bounds__(256) void k_cls(const float* __restrict__ z, const float* __restrict__ Wc1,
                                             const float* __restrict__ bc1, const float* __restrict__ Wc2,
                                             const float* __restrict__ bc2, float* __restrict__ out, int G) {
  __shared__ __align__(16) float w1s[64 * H];
  __shared__ float w2s[H * 2], b1s[H], b2s[2];
  int t = threadIdx.x;
  for (int i = t; i < 64 * H; i += 256) w1s[i] = Wc1[i];
  if (t < H * 2) w2s[t] = Wc2[t];
  if (t < H) b1s[t] = bc1[t];
  if (t < 2) b2s[t] = bc2[t];
  __syncthreads();
  int g = blockIdx.x * 256 + t;
  if (g >= G) return;
  float zr[64], u[H];
  const float4* zp = (const float4*)&z[(size_t)g * 64];
#pragma unroll
  for (int q = 0; q < 16; ++q) {
    float4 v = zp[q];
    zr[q * 4 + 0] = v.x; zr[q * 4 + 1] = v.y; zr[q * 4 + 2] = v.z; zr[q * 4 + 3] = v.w;
  }
#pragma unroll
  for (int c = 0; c < H; ++c) u[c] = b1s[c];
#pragma unroll
  for (int k = 0; k < 64; ++k) {
    float av = zr[k];
    const float4* wr = (const float4*)&w1s[k * H];
#pragma unroll
    for (int q = 0; q < H / 4; ++q) {
      float4 wv = wr[q];
      u[q * 4 + 0] += av * wv.x; u[q * 4 + 1] += av * wv.y;
      u[q * 4 + 2] += av * wv.z; u[q * 4 + 3] += av * wv.w;
    }
  }
  float o0 = b2s[0], o1 = b2s[1];
#pragma unroll
  for (int k = 0; k < H; ++k) {
    float uv = fmaxf(u[k], 0.f);
    o0 += uv * w2s[k * 2 + 0];
    o1 += uv * w2s[k * 2 + 1];
  }
  out[(size_t)g * 2 + 0] = o0;
  out[(size_t)g * 2 + 1] = o1;
}

extern "C" void kernel_launch(void* const* d_in, const int* in_sizes, int n_in,
                              void* d_out, int out_size, void* d_ws, size_t ws_size,
                              hipStream_t stream) {
  const float* x    = (const float*)d_in[0];
  const int*   eidx = (const int*)d_in[1];
  const int*   batch= (const int*)d_in[2];
  const float* W1 = (const float*)d_in[3];
  const float* b1 = (const float*)d_in[4];
  const float* g1 = (const float*)d_in[5];
  const float* be1= (const float*)d_in[6];
  const float* W2 = (const float*)d_in[7];
  const float* b2 = (const float*)d_in[8];
  const float* W3 = (const float*)d_in[9];
  const float* b3 = (const float*)d_in[10];
  const float* g2 = (const float*)d_in[11];
  const float* be2= (const float*)d_in[12];
  const float* W4 = (const float*)d_in[13];
  const float* b4 = (const float*)d_in[14];
  const float* Wc1= (const float*)d_in[15];
  const float* bc1= (const float*)d_in[16];
  const float* Wc2= (const float*)d_in[17];
  const float* bc2= (const float*)d_in[18];
  (void)n_in; (void)ws_size;

  int N = in_sizes[2];       // 100000
  int E = in_sizes[1] / 2;   // 1600000
  int G = out_size / 2;      // 1000
  const int* srcv = eidx;
  const int* dstv = eidx + E;

  char* w = (char*)d_ws;
  auto carve = [&](size_t bytes) { void* p = (void*)w; w += (bytes + 255) & ~(size_t)255; return p; };
  float* bufA   = (float*)carve((size_t)N * H * 4);      // y1 -> y2 -> h2
  float* bufB   = (float*)carve((size_t)N * H * 4);      // h1 -> h2pre
  int*   counts = (int*)carve((size_t)N * 4);
  int*   row_ptr= (int*)carve((size_t)(N + 1) * 4);
  int*   cursor = (int*)carve((size_t)N * 4);
  int*   csr    = (int*)carve((size_t)E * 4);
  int*   blocksum = (int*)carve((size_t)SCAN_NB * 4);
  int*   blockoff = (int*)carve((size_t)(SCAN_NB + 1) * 4);
  float* bnp    = (float*)carve((size_t)AGG_BLOCKS * 64 * 4);
  float* sc1    = (float*)carve(64 * 4);
  float* sc2    = (float*)carve(64 * 4);
  float* z      = (float*)carve((size_t)G * 64 * 4);

  hipMemsetAsync(counts, 0, (size_t)N * 4, stream);
  k_hist<<<(E + 255) / 256, 256, 0, stream>>>(dstv, E, counts);
  k_scan_part<<<SCAN_NB, SCAN_BT, 0, stream>>>(counts, N, blocksum);
  k_scan_top<<<1, SCAN_NB, 0, stream>>>(blocksum, blockoff);
  k_scan_out<<<SCAN_NB, SCAN_BT, 0, stream>>>(counts, N, blockoff, row_ptr, cursor);
  k_scatter<<<(E + 255) / 256, 256, 0, stream>>>(srcv, dstv, E, cursor, csr);
  k_gemm1<<<(N + 127) / 128, 256, 0, stream>>>(x, W1, bufA, N);
  k_agg<<<AGG_BLOCKS, 256, 0, stream>>>(bufA, b1, row_ptr, csr, bufB, bnp, N);
  k_bnfin<<<1, 256, 0, stream>>>(bnp, AGG_BLOCKS, g1, be1, sc1, 1.0f / (float)N);
  k_mlp1<<<(N + 255) / 256, 256, 0, stream>>>(bufB, sc1, W2, b2, W3, bufA, N);
  k_agg<<<AGG_BLOCKS, 256, 0, stream>>>(bufA, b3, row_ptr, csr, bufB, bnp, N);
  k_bnfin<<<1, 256, 0, stream>>>(bnp, AGG_BLOCKS, g2, be2, sc2, 1.0f / (float)N);
  k_mlp2<<<(N + 255) / 256, 256, 0, stream>>>(bufB, sc2, W4, b4, bufA, N);
  k_pool<<<(G + 3) / 4, 256, 0, stream>>>(bufA, batch, N, G, z);
  k_cls<<<(G + 255) / 256, 256, 0, stream>>>(z, Wc1, bc1, Wc2, bc2, (float*)d_out, G);
}

// Round 6
// 569.033 us; speedup vs baseline: 1.9270x; 1.4788x over previous
//
#include <hip/hip_runtime.h>

// GIN-2layer + pool + classifier for MI355X.
// R5 change (measured: k_bnfin 148us x2 @ 0.046% occupancy = 35% of runtime):
//   BN partial reduction made hierarchical: k_bnred (64 blocks) reduces
//   2048x64 -> 64x64, then k_bnfin (1 block) reduces 64x64 -> scale/shift.
// Kept: 3-phase scan (R2), wave-uniform shfl broadcast in k_agg (R4 fix).

#define H 32
#define FIN 128
#define AGG_BLOCKS 2048
#define BNRED_NB 64   // stage-A blocks; each reduces AGG_BLOCKS/BNRED_NB = 32 rows

#define SCAN_NB 256
#define SCAN_BT 256
#define SCAN_T  2   // elements per thread; NB*BT*T = 131072 >= N

__device__ __forceinline__ int lower_bound_i(const int* __restrict__ a, int n, int key) {
  int lo = 0, hi = n;
  while (lo < hi) { int mid = (lo + hi) >> 1; if (a[mid] < key) lo = mid + 1; else hi = mid; }
  return lo;
}

__global__ void k_hist(const int* __restrict__ dst, int E, int* __restrict__ counts) {
  int i = blockIdx.x * blockDim.x + threadIdx.x;
  if (i < E) atomicAdd(&counts[dst[i]], 1);
}

// ---- 3-phase scan ----
__global__ __launch_bounds__(SCAN_BT) void k_scan_part(const int* __restrict__ counts, int N,
                                                       int* __restrict__ blocksum) {
  int t = threadIdx.x, b = blockIdx.x;
  int base = (b * SCAN_BT + t) * SCAN_T;
  int s = 0;
#pragma unroll
  for (int i = 0; i < SCAN_T; ++i) {
    int idx = base + i;
    if (idx < N) s += counts[idx];
  }
  __shared__ int red[SCAN_BT];
  red[t] = s;
  __syncthreads();
  for (int d = SCAN_BT / 2; d > 0; d >>= 1) {
    if (t < d) red[t] += red[t + d];
    __syncthreads();
  }
  if (t == 0) blocksum[b] = red[0];
}

__global__ __launch_bounds__(SCAN_NB) void k_scan_top(const int* __restrict__ blocksum,
                                                      int* __restrict__ blockoff) {
  int t = threadIdx.x;
  __shared__ int sh[SCAN_NB];
  sh[t] = blocksum[t];
  __syncthreads();
  for (int d = 1; d < SCAN_NB; d <<= 1) {
    int v = (t >= d) ? sh[t - d] : 0;
    __syncthreads();
    sh[t] += v;
    __syncthreads();
  }
  blockoff[t] = (t == 0) ? 0 : sh[t - 1];
  if (t == SCAN_NB - 1) blockoff[SCAN_NB] = sh[t];
}

__global__ __launch_bounds__(SCAN_BT) void k_scan_out(const int* __restrict__ counts, int N,
                                                      const int* __restrict__ blockoff,
                                                      int* __restrict__ row_ptr, int* __restrict__ cursor) {
  int t = threadIdx.x, b = blockIdx.x;
  int base = (b * SCAN_BT + t) * SCAN_T;
  int v0 = (base < N) ? counts[base] : 0;
  int v1 = (base + 1 < N) ? counts[base + 1] : 0;
  __shared__ int sh[SCAN_BT];
  sh[t] = v0 + v1;
  __syncthreads();
  for (int d = 1; d < SCAN_BT; d <<= 1) {
    int v = (t >= d) ? sh[t - d] : 0;
    __syncthreads();
    sh[t] += v;
    __syncthreads();
  }
  int run = blockoff[b] + ((t == 0) ? 0 : sh[t - 1]);
  if (base < N)     { row_ptr[base] = run; cursor[base] = run; run += v0; }
  if (base + 1 < N) { row_ptr[base + 1] = run; cursor[base + 1] = run; }
  if (b == 0 && t == 0) row_ptr[N] = blockoff[SCAN_NB];
}

__global__ void k_scatter(const int* __restrict__ src, const int* __restrict__ dst, int E,
                          int* __restrict__ cursor, int* __restrict__ csr) {
  int i = blockIdx.x * blockDim.x + threadIdx.x;
  if (i < E) {
    int p = atomicAdd(&cursor[dst[i]], 1);
    csr[p] = src[i];
  }
}

// y[N,32] = x[N,128] @ W[128,32].  128 nodes/block, thread tile 4 nodes x 4 cols.
__global__ __launch_bounds__(256) void k_gemm1(const float* __restrict__ x, const float* __restrict__ W,
                                               float* __restrict__ y, int N) {
  __shared__ __align__(16) float ws[FIN * H];   // 16 KB, [k][c]
  __shared__ __align__(16) float xs[128 * 33];  // k-chunk of 32 (+1 pad)
  int t = threadIdx.x;
  for (int i = t; i < FIN * H; i += 256) ws[i] = W[i];
  int nb = blockIdx.x * 128;
  int r0 = (t >> 3) * 4;   // 0..124
  int c0 = (t & 7) * 4;    // 0..28
  float acc[4][4] = {{0.f,0.f,0.f,0.f},{0.f,0.f,0.f,0.f},{0.f,0.f,0.f,0.f},{0.f,0.f,0.f,0.f}};
  for (int kb = 0; kb < FIN; kb += 32) {
    __syncthreads();
    for (int i = t; i < 1024; i += 256) {  // 1024 float4 = [128][32] chunk
      int n = i >> 3, k4 = (i & 7) * 4;
      float4 v = make_float4(0.f, 0.f, 0.f, 0.f);
      int gn = nb + n;
      if (gn < N) v = *(const float4*)&x[(size_t)gn * FIN + kb + k4];
      xs[n * 33 + k4 + 0] = v.x; xs[n * 33 + k4 + 1] = v.y;
      xs[n * 33 + k4 + 2] = v.z; xs[n * 33 + k4 + 3] = v.w;
    }
    __syncthreads();
#pragma unroll
    for (int k = 0; k < 32; ++k) {
      float4 wv = *(const float4*)&ws[(kb + k) * H + c0];
      float x0 = xs[(r0 + 0) * 33 + k];
      float x1 = xs[(r0 + 1) * 33 + k];
      float x2 = xs[(r0 + 2) * 33 + k];
      float x3 = xs[(r0 + 3) * 33 + k];
      acc[0][0] += x0 * wv.x; acc[0][1] += x0 * wv.y; acc[0][2] += x0 * wv.z; acc[0][3] += x0 * wv.w;
      acc[1][0] += x1 * wv.x; acc[1][1] += x1 * wv.y; acc[1][2] += x1 * wv.z; acc[1][3] += x1 * wv.w;
      acc[2][0] += x2 * wv.x; acc[2][1] += x2 * wv.y; acc[2][2] += x2 * wv.z; acc[2][3] += x2 * wv.w;
      acc[3][0] += x3 * wv.x; acc[3][1] += x3 * wv.y; acc[3][2] += x3 * wv.z; acc[3][3] += x3 * wv.w;
    }
  }
#pragma unroll
  for (int r = 0; r < 4; ++r) {
    int gn = nb + r0 + r;
    if (gn < N)
      *(float4*)&y[(size_t)gn * H + c0] = make_float4(acc[r][0], acc[r][1], acc[r][2], acc[r][3]);
  }
}

// hout[n] = y[n] + bias + sum_{j in in(n)} y[j];  also per-block BN partials (sum, sumsq).
// One wave per node. csr indices loaded 64-wide coalesced, broadcast via shfl.
// Broadcast loop is WAVE-UNIFORM so every ds_bpermute source lane is active.
__global__ __launch_bounds__(256) void k_agg(const float* __restrict__ y, const float* __restrict__ bias,
                                             const int* __restrict__ row_ptr, const int* __restrict__ csr,
                                             float* __restrict__ hout, float* __restrict__ bn_part, int N) {
  int wid = threadIdx.x >> 6, lane = threadIdx.x & 63;
  int c = lane & 31, ep = lane >> 5;
  float rsum = 0.f, rsq = 0.f;
  float bc = bias[c];
  int stride = gridDim.x * 4;
  for (int n = blockIdx.x * 4 + wid; n < N; n += stride) {
    int beg = row_ptr[n], end = row_ptr[n + 1];
    float acc = 0.f;
    for (int b0 = beg; b0 < end; b0 += 64) {
      int m = end - b0; if (m > 64) m = 64;          // wave-uniform
      int idx = (lane < m) ? csr[b0 + lane] : 0;
      for (int r = 0; r < m; r += 2) {               // uniform trip count
        int s = r + ep;                              // may be == m when m odd, ep==1
        int j = __shfl(idx, (s < m) ? s : 0, 64);    // full-exec shfl, valid src
        float val = y[(size_t)j * H + c];
        if (s < m) acc += val;                       // predicated accumulate
      }
    }
    acc += __shfl_xor(acc, 32, 64);
    float v = acc + y[(size_t)n * H + c] + bc;
    if (ep == 0) {
      hout[(size_t)n * H + c] = v;
      rsum += v; rsq += v * v;
    }
  }
  __shared__ float bsum[4][H], bsq[4][H];
  if (ep == 0) { bsum[wid][c] = rsum; bsq[wid][c] = rsq; }
  __syncthreads();
  if (threadIdx.x < H) {
    int cc = threadIdx.x;
    bn_part[(size_t)blockIdx.x * 64 + cc]     = bsum[0][cc] + bsum[1][cc] + bsum[2][cc] + bsum[3][cc];
    bn_part[(size_t)blockIdx.x * 64 + H + cc] = bsq[0][cc] + bsq[1][cc] + bsq[2][cc] + bsq[3][cc];
  }
}

// Stage A: 64 blocks, block b reduces rows [32b, 32b+32) of part[2048][64] -> part2[b][64].
__global__ __launch_bounds__(256) void k_bnred(const float* __restrict__ part,
                                               float* __restrict__ part2) {
  int t = threadIdx.x, b = blockIdx.x;
  int col = t & 63, q = t >> 6;                       // 4 row-groups x 8 rows
  int rpb = AGG_BLOCKS / BNRED_NB;                    // 32
  int r0 = b * rpb + q * (rpb / 4);
  float s = 0.f;
  for (int r = r0; r < r0 + rpb / 4; ++r) s += part[(size_t)r * 64 + col];
  __shared__ float red[4][64];
  red[q][col] = s;
  __syncthreads();
  if (t < 64) part2[(size_t)b * 64 + t] = red[0][t] + red[1][t] + red[2][t] + red[3][t];
}

// Stage B: 1 block reduces part[nblk][64] (nblk=64 now) -> scale/shift.
__global__ __launch_bounds__(256) void k_bnfin(const float* __restrict__ part, int nblk,
                                               const float* __restrict__ gma, const float* __restrict__ bet,
                                               float* __restrict__ sc, float invN) {
  int t = threadIdx.x;
  int col = t & 63, q = t >> 6;   // 4 slices
  int per = nblk >> 2;
  float s = 0.f;
  for (int r = q * per; r < (q + 1) * per; ++r) s += part[(size_t)r * 64 + col];
  __shared__ float red[4][64];
  __shared__ float tot[64];
  red[q][col] = s;
  __syncthreads();
  if (t < 64) tot[t] = red[0][t] + red[1][t] + red[2][t] + red[3][t];
  __syncthreads();
  if (t < H) {
    float mean = tot[t] * invN;
    float var = tot[H + t] * invN - mean * mean;
    float scale = gma[t] * rsqrtf(var + 1e-5f);
    sc[t] = scale;
    sc[H + t] = bet[t] - mean * scale;
  }
}

// y2 = relu(relu(BN1(h1)) @ W2 + b2) @ W3 ; thread per node, W in LDS (uniform broadcast reads).
__global__ __launch_bounds__(256) void k_mlp1(const float* __restrict__ h1, const float* __restrict__ sc,
                                              const float* __restrict__ W2, const float* __restrict__ b2,
                                              const float* __restrict__ W3, float* __restrict__ y2, int N) {
  __shared__ __align__(16) float ws2[H * H], ws3[H * H];
  __shared__ float scale_s[H], shift_s[H], b2s[H];
  int t = threadIdx.x;
  for (int i = t; i < H * H; i += 256) { ws2[i] = W2[i]; ws3[i] = W3[i]; }
  if (t < H) { scale_s[t] = sc[t]; shift_s[t] = sc[H + t]; b2s[t] = b2[t]; }
  __syncthreads();
  int n = blockIdx.x * 256 + t;
  if (n >= N) return;
  float a[H], u[H], o[H];
  const float4* hin = (const float4*)&h1[(size_t)n * H];
#pragma unroll
  for (int q = 0; q < H / 4; ++q) {
    float4 v = hin[q];
    a[q * 4 + 0] = fmaxf(v.x * scale_s[q * 4 + 0] + shift_s[q * 4 + 0], 0.f);
    a[q * 4 + 1] = fmaxf(v.y * scale_s[q * 4 + 1] + shift_s[q * 4 + 1], 0.f);
    a[q * 4 + 2] = fmaxf(v.z * scale_s[q * 4 + 2] + shift_s[q * 4 + 2], 0.f);
    a[q * 4 + 3] = fmaxf(v.w * scale_s[q * 4 + 3] + shift_s[q * 4 + 3], 0.f);
  }
#pragma unroll
  for (int c = 0; c < H; ++c) u[c] = b2s[c];
#pragma unroll
  for (int k = 0; k < H; ++k) {
    float av = a[k];
    const float4* wr = (const float4*)&ws2[k * H];
#pragma unroll
    for (int q = 0; q < H / 4; ++q) {
      float4 wv = wr[q];
      u[q * 4 + 0] += av * wv.x; u[q * 4 + 1] += av * wv.y;
      u[q * 4 + 2] += av * wv.z; u[q * 4 + 3] += av * wv.w;
    }
  }
#pragma unroll
  for (int c = 0; c < H; ++c) { u[c] = fmaxf(u[c], 0.f); o[c] = 0.f; }
#pragma unroll
  for (int k = 0; k < H; ++k) {
    float av = u[k];
    const float4* wr = (const float4*)&ws3[k * H];
#pragma unroll
    for (int q = 0; q < H / 4; ++q) {
      float4 wv = wr[q];
      o[q * 4 + 0] += av * wv.x; o[q * 4 + 1] += av * wv.y;
      o[q * 4 + 2] += av * wv.z; o[q * 4 + 3] += av * wv.w;
    }
  }
  float4* yo = (float4*)&y2[(size_t)n * H];
#pragma unroll
  for (int q = 0; q < H / 4; ++q)
    yo[q] = make_float4(o[q * 4 + 0], o[q * 4 + 1], o[q * 4 + 2], o[q * 4 + 3]);
}

// h2 = relu(BN2(h2pre)) @ W4 + b4   (no trailing relu)
__global__ __launch_bounds__(256) void k_mlp2(const float* __restrict__ hpre, const float* __restrict__ sc,
                                              const float* __restrict__ W4, const float* __restrict__ b4,
                                              float* __restrict__ h2, int N) {
  __shared__ __align__(16) float ws4[H * H];
  __shared__ float scale_s[H], shift_s[H], b4s[H];
  int t = threadIdx.x;
  for (int i = t; i < H * H; i += 256) ws4[i] = W4[i];
  if (t < H) { scale_s[t] = sc[t]; shift_s[t] = sc[H + t]; b4s[t] = b4[t]; }
  __syncthreads();
  int n = blockIdx.x * 256 + t;
  if (n >= N) return;
  float a[H], o[H];
  const float4* hin = (const float4*)&hpre[(size_t)n * H];
#pragma unroll
  for (int q = 0; q < H / 4; ++q) {
    float4 v = hin[q];
    a[q * 4 + 0] = fmaxf(v.x * scale_s[q * 4 + 0] + shift_s[q * 4 + 0], 0.f);
    a[q * 4 + 1] = fmaxf(v.y * scale_s[q * 4 + 1] + shift_s[q * 4 + 1], 0.f);
    a[q * 4 + 2] = fmaxf(v.z * scale_s[q * 4 + 2] + shift_s[q * 4 + 2], 0.f);
    a[q * 4 + 3] = fmaxf(v.w * scale_s[q * 4 + 3] + shift_s[q * 4 + 3], 0.f);
  }
#pragma unroll
  for (int c = 0; c < H; ++c) o[c] = b4s[c];
#pragma unroll
  for (int k = 0; k < H; ++k) {
    float av = a[k];
    const float4* wr = (const float4*)&ws4[k * H];
#pragma unroll
    for (int q = 0; q < H / 4; ++q) {
      float4 wv = wr[q];
      o[q * 4 + 0] += av * wv.x; o[q * 4 + 1] += av * wv.y;
      o[q * 4 + 2] += av * wv.z; o[q * 4 + 3] += av * wv.w;
    }
  }
  float4* ho = (float4*)&h2[(size_t)n * H];
#pragma unroll
  for (int q = 0; q < H / 4; ++q)
    ho[q] = make_float4(o[q * 4 + 0], o[q * 4 + 1], o[q * 4 + 2], o[q * 4 + 3]);
}

// batch is sorted: graph g owns node range [lb(g), lb(g+1)). Wave per graph, mean||max -> z[G,64].
__global__ __launch_bounds__(256) void k_pool(const float* __restrict__ h2, const int* __restrict__ batch,
                                              int N, int G, float* __restrict__ z) {
  int wid = threadIdx.x >> 6, lane = threadIdx.x & 63;
  int g = blockIdx.x * 4 + wid;
  if (g >= G) return;
  int beg = lower_bound_i(batch, N, g);
  int end = lower_bound_i(batch, N, g + 1);
  int c = lane & 31, ep = lane >> 5;
  float s = 0.f, m = -3.402823466e38f;
  for (int i = beg + ep; i < end; i += 2) {
    float v = h2[(size_t)i * H + c];
    s += v; m = fmaxf(m, v);
  }
  s += __shfl_xor(s, 32, 64);
  m = fmaxf(m, __shfl_xor(m, 32, 64));
  if (ep == 0) {
    int cnt = end - beg;
    z[(size_t)g * 64 + c]     = (cnt > 0) ? s / (float)cnt : 0.f;
    z[(size_t)g * 64 + H + c] = (cnt > 0) ? m : 0.f;
  }
}

// out = relu(z @ Wc1 + bc1) @ Wc2 + bc2 ; thread per graph.
__global__ __launch_bounds__(256) void k_cls(const float* __restrict__ z, const float* __restrict__ Wc1,
                                             const float* __restrict__ bc1, const float* __restrict__ Wc2,
                                             const float* __restrict__ bc2, float* __restrict__ out, int G) {
  __shared__ __align__(16) float w1s[64 * H];
  __shared__ float w2s[H * 2], b1s[H], b2s[2];
  int t = threadIdx.x;
  for (int i = t; i < 64 * H; i += 256) w1s[i] = Wc1[i];
  if (t < H * 2) w2s[t] = Wc2[t];
  if (t < H) b1s[t] = bc1[t];
  if (t < 2) b2s[t] = bc2[t];
  __syncthreads();
  int g = blockIdx.x * 256 + t;
  if (g >= G) return;
  float zr[64], u[H];
  const float4* zp = (const float4*)&z[(size_t)g * 64];
#pragma unroll
  for (int q = 0; q < 16; ++q) {
    float4 v = zp[q];
    zr[q * 4 + 0] = v.x; zr[q * 4 + 1] = v.y; zr[q * 4 + 2] = v.z; zr[q * 4 + 3] = v.w;
  }
#pragma unroll
  for (int c = 0; c < H; ++c) u[c] = b1s[c];
#pragma unroll
  for (int k = 0; k < 64; ++k) {
    float av = zr[k];
    const float4* wr = (const float4*)&w1s[k * H];
#pragma unroll
    for (int q = 0; q < H / 4; ++q) {
      float4 wv = wr[q];
      u[q * 4 + 0] += av * wv.x; u[q * 4 + 1] += av * wv.y;
      u[q * 4 + 2] += av * wv.z; u[q * 4 + 3] += av * wv.w;
    }
  }
  float o0 = b2s[0], o1 = b2s[1];
#pragma unroll
  for (int k = 0; k < H; ++k) {
    float uv = fmaxf(u[k], 0.f);
    o0 += uv * w2s[k * 2 + 0];
    o1 += uv * w2s[k * 2 + 1];
  }
  out[(size_t)g * 2 + 0] = o0;
  out[(size_t)g * 2 + 1] = o1;
}

extern "C" void kernel_launch(void* const* d_in, const int* in_sizes, int n_in,
                              void* d_out, int out_size, void* d_ws, size_t ws_size,
                              hipStream_t stream) {
  const float* x    = (const float*)d_in[0];
  const int*   eidx = (const int*)d_in[1];
  const int*   batch= (const int*)d_in[2];
  const float* W1 = (const float*)d_in[3];
  const float* b1 = (const float*)d_in[4];
  const float* g1 = (const float*)d_in[5];
  const float* be1= (const float*)d_in[6];
  const float* W2 = (const float*)d_in[7];
  const float* b2 = (const float*)d_in[8];
  const float* W3 = (const float*)d_in[9];
  const float* b3 = (const float*)d_in[10];
  const float* g2 = (const float*)d_in[11];
  const float* be2= (const float*)d_in[12];
  const float* W4 = (const float*)d_in[13];
  const float* b4 = (const float*)d_in[14];
  const float* Wc1= (const float*)d_in[15];
  const float* bc1= (const float*)d_in[16];
  const float* Wc2= (const float*)d_in[17];
  const float* bc2= (const float*)d_in[18];
  (void)n_in; (void)ws_size;

  int N = in_sizes[2];       // 100000
  int E = in_sizes[1] / 2;   // 1600000
  int G = out_size / 2;      // 1000
  const int* srcv = eidx;
  const int* dstv = eidx + E;

  char* w = (char*)d_ws;
  auto carve = [&](size_t bytes) { void* p = (void*)w; w += (bytes + 255) & ~(size_t)255; return p; };
  float* bufA   = (float*)carve((size_t)N * H * 4);      // y1 -> y2 -> h2
  float* bufB   = (float*)carve((size_t)N * H * 4);      // h1 -> h2pre
  int*   counts = (int*)carve((size_t)N * 4);
  int*   row_ptr= (int*)carve((size_t)(N + 1) * 4);
  int*   cursor = (int*)carve((size_t)N * 4);
  int*   csr    = (int*)carve((size_t)E * 4);
  int*   blocksum = (int*)carve((size_t)SCAN_NB * 4);
  int*   blockoff = (int*)carve((size_t)(SCAN_NB + 1) * 4);
  float* bnp    = (float*)carve((size_t)AGG_BLOCKS * 64 * 4);
  float* bnp2   = (float*)carve((size_t)BNRED_NB * 64 * 4);
  float* sc1    = (float*)carve(64 * 4);
  float* sc2    = (float*)carve(64 * 4);
  float* z      = (float*)carve((size_t)G * 64 * 4);

  hipMemsetAsync(counts, 0, (size_t)N * 4, stream);
  k_hist<<<(E + 255) / 256, 256, 0, stream>>>(dstv, E, counts);
  k_scan_part<<<SCAN_NB, SCAN_BT, 0, stream>>>(counts, N, blocksum);
  k_scan_top<<<1, SCAN_NB, 0, stream>>>(blocksum, blockoff);
  k_scan_out<<<SCAN_NB, SCAN_BT, 0, stream>>>(counts, N, blockoff, row_ptr, cursor);
  k_scatter<<<(E + 255) / 256, 256, 0, stream>>>(srcv, dstv, E, cursor, csr);
  k_gemm1<<<(N + 127) / 128, 256, 0, stream>>>(x, W1, bufA, N);
  k_agg<<<AGG_BLOCKS, 256, 0, stream>>>(bufA, b1, row_ptr, csr, bufB, bnp, N);
  k_bnred<<<BNRED_NB, 256, 0, stream>>>(bnp, bnp2);
  k_bnfin<<<1, 256, 0, stream>>>(bnp2, BNRED_NB, g1, be1, sc1, 1.0f / (float)N);
  k_mlp1<<<(N + 255) / 256, 256, 0, stream>>>(bufB, sc1, W2, b2, W3, bufA, N);
  k_agg<<<AGG_BLOCKS, 256, 0, stream>>>(bufA, b3, row_ptr, csr, bufB, bnp, N);
  k_bnred<<<BNRED_NB, 256, 0, stream>>>(bnp, bnp2);
  k_bnfin<<<1, 256, 0, stream>>>(bnp2, BNRED_NB, g2, be2, sc2, 1.0f / (float)N);
  k_mlp2<<<(N + 255) / 256, 256, 0, stream>>>(bufB, sc2, W4, b4, bufA, N);
  k_pool<<<(G + 3) / 4, 256, 0, stream>>>(bufA, batch, N, G, z);
  k_cls<<<(G + 255) / 256, 256, 0, stream>>>(z, Wc1, bc1, Wc2, bc2, (float*)d_out, G);
}

// Round 7
// 433.444 us; speedup vs baseline: 2.5298x; 1.3128x over previous
//
#include <hip/hip_runtime.h>

// GIN-2layer + pool + classifier for MI355X.
// R6 change (measured: k_scatter 130us, WRITE_SIZE=105MB for 6.4MB payload ->
// 64B/edge line-granular write amplification on random 4B scatter):
//   CSR build replaced by two-level counting sort:
//     k_bhist  : coarse 196-bucket histogram (LDS + 196 atomics/block)
//     k_bscan  : 1-block scan of bucket sizes -> bbase/bcur
//     k_bucketA: reserve per-(block,bucket) runs, append packed (dstlow|src)
//                -> writes are contiguous runs, ~6.4MB instead of 105MB
//     k_bucketB: per-bucket (512 nodes, 32KB csr window) LDS hist + scan,
//                writes row_ptr slice AND dst-sorted csr (L2-resident window)
//   This also removes k_hist (1.6M random global atomics) and the 3 scan
//   kernels: row_ptr now falls out of the bucket sort.
// Kept: hierarchical BN reduce (R5), wave-uniform shfl in k_agg (R4), rest.
// NOTE: packing uses 17 bits for src (requires N <= 131072; problem has N=100000).

#define H 32
#define FIN 128
#define AGG_BLOCKS 2048
#define BNRED_NB 64

#define BKT_SHIFT 9
#define BKT_SZ 512          // nodes per bucket; nbuck = ceil(N/512) = 196 <= 256
#define ACHUNK 4096         // edges per block in bhist/bucketA

__device__ __forceinline__ int lower_bound_i(const int* __restrict__ a, int n, int key) {
  int lo = 0, hi = n;
  while (lo < hi) { int mid = (lo + hi) >> 1; if (a[mid] < key) lo = mid + 1; else hi = mid; }
  return lo;
}

// ---- CSR build: two-level counting sort ----

__global__ __launch_bounds__(256) void k_bhist(const int* __restrict__ dst, int E,
                                               int* __restrict__ gbcnt) {
  __shared__ int cnt[256];
  int t = threadIdx.x;
  int e0 = blockIdx.x * ACHUNK, e1 = min(e0 + ACHUNK, E);
  cnt[t] = 0;
  __syncthreads();
  for (int i = e0 + t; i < e1; i += 256) atomicAdd(&cnt[dst[i] >> BKT_SHIFT], 1);
  __syncthreads();
  if (cnt[t] > 0) atomicAdd(&gbcnt[t], cnt[t]);
}

__global__ __launch_bounds__(256) void k_bscan(const int* __restrict__ gbcnt, int nbuck,
                                               int* __restrict__ bbase, int* __restrict__ bcur) {
  int t = threadIdx.x;
  __shared__ int sh[256];
  int v0 = (t < nbuck) ? gbcnt[t] : 0;
  sh[t] = v0;
  __syncthreads();
  for (int d = 1; d < 256; d <<= 1) {
    int v = (t >= d) ? sh[t - d] : 0;
    __syncthreads();
    sh[t] += v;
    __syncthreads();
  }
  int excl = sh[t] - v0;
  if (t < nbuck) { bbase[t] = excl; bcur[t] = excl; }
  if (t == 255) bbase[nbuck] = sh[255];
}

__global__ __launch_bounds__(256) void k_bucketA(const int* __restrict__ src, const int* __restrict__ dst,
                                                 int E, int* __restrict__ bcur,
                                                 unsigned* __restrict__ staging) {
  __shared__ int cnt[256];
  __shared__ int base[256];
  int t = threadIdx.x;
  int e0 = blockIdx.x * ACHUNK, e1 = min(e0 + ACHUNK, E);
  cnt[t] = 0;
  __syncthreads();
  for (int i = e0 + t; i < e1; i += 256) atomicAdd(&cnt[dst[i] >> BKT_SHIFT], 1);
  __syncthreads();
  int c = cnt[t];
  base[t] = (c > 0) ? atomicAdd(&bcur[t], c) : 0;
  __syncthreads();
  for (int i = e0 + t; i < e1; i += 256) {
    int d = dst[i];
    int p = atomicAdd(&base[d >> BKT_SHIFT], 1);
    staging[p] = ((unsigned)(d & (BKT_SZ - 1)) << 17) | (unsigned)src[i];
  }
}

// One block per bucket: per-node hist (512) + scan -> row_ptr slice + sorted csr.
__global__ __launch_bounds__(256) void k_bucketB(const unsigned* __restrict__ staging,
                                                 const int* __restrict__ bbase, int N,
                                                 int* __restrict__ row_ptr, int* __restrict__ csr) {
  __shared__ int cnt[BKT_SZ];
  __shared__ int ptr[BKT_SZ];
  __shared__ int sc[256];
  int t = threadIdx.x, b = blockIdx.x;
  int nb0 = b << BKT_SHIFT;
  int nb1 = min(nb0 + BKT_SZ, N);
  int seg0 = bbase[b];
  int len = bbase[b + 1] - seg0;
  cnt[t] = 0; cnt[t + 256] = 0;
  __syncthreads();
  for (int i = t; i < len; i += 256) atomicAdd(&cnt[staging[seg0 + i] >> 17], 1);
  __syncthreads();
  int s2 = cnt[2 * t] + cnt[2 * t + 1];
  sc[t] = s2;
  __syncthreads();
  for (int d = 1; d < 256; d <<= 1) {
    int v = (t >= d) ? sc[t - d] : 0;
    __syncthreads();
    sc[t] += v;
    __syncthreads();
  }
  int base0 = sc[t] - s2;
  ptr[2 * t] = base0;
  ptr[2 * t + 1] = base0 + cnt[2 * t];
  __syncthreads();
  int nn = nb1 - nb0;
  if (2 * t < nn)     row_ptr[nb0 + 2 * t]     = seg0 + ptr[2 * t];
  if (2 * t + 1 < nn) row_ptr[nb0 + 2 * t + 1] = seg0 + ptr[2 * t + 1];
  if (t == 0 && nb1 == N) row_ptr[N] = seg0 + len;
  __syncthreads();
  for (int i = t; i < len; i += 256) {
    unsigned e = staging[seg0 + i];
    int d = (int)(e >> 17);
    int k = atomicAdd(&ptr[d], 1);
    csr[seg0 + k] = (int)(e & 0x1FFFFu);
  }
}

// ---- main pipeline kernels (unchanged from R5) ----

// y[N,32] = x[N,128] @ W[128,32].  128 nodes/block, thread tile 4 nodes x 4 cols.
__global__ __launch_bounds__(256) void k_gemm1(const float* __restrict__ x, const float* __restrict__ W,
                                               float* __restrict__ y, int N) {
  __shared__ __align__(16) float ws[FIN * H];   // 16 KB, [k][c]
  __shared__ __align__(16) float xs[128 * 33];  // k-chunk of 32 (+1 pad)
  int t = threadIdx.x;
  for (int i = t; i < FIN * H; i += 256) ws[i] = W[i];
  int nb = blockIdx.x * 128;
  int r0 = (t >> 3) * 4;   // 0..124
  int c0 = (t & 7) * 4;    // 0..28
  float acc[4][4] = {{0.f,0.f,0.f,0.f},{0.f,0.f,0.f,0.f},{0.f,0.f,0.f,0.f},{0.f,0.f,0.f,0.f}};
  for (int kb = 0; kb < FIN; kb += 32) {
    __syncthreads();
    for (int i = t; i < 1024; i += 256) {  // 1024 float4 = [128][32] chunk
      int n = i >> 3, k4 = (i & 7) * 4;
      float4 v = make_float4(0.f, 0.f, 0.f, 0.f);
      int gn = nb + n;
      if (gn < N) v = *(const float4*)&x[(size_t)gn * FIN + kb + k4];
      xs[n * 33 + k4 + 0] = v.x; xs[n * 33 + k4 + 1] = v.y;
      xs[n * 33 + k4 + 2] = v.z; xs[n * 33 + k4 + 3] = v.w;
    }
    __syncthreads();
#pragma unroll
    for (int k = 0; k < 32; ++k) {
      float4 wv = *(const float4*)&ws[(kb + k) * H + c0];
      float x0 = xs[(r0 + 0) * 33 + k];
      float x1 = xs[(r0 + 1) * 33 + k];
      float x2 = xs[(r0 + 2) * 33 + k];
      float x3 = xs[(r0 + 3) * 33 + k];
      acc[0][0] += x0 * wv.x; acc[0][1] += x0 * wv.y; acc[0][2] += x0 * wv.z; acc[0][3] += x0 * wv.w;
      acc[1][0] += x1 * wv.x; acc[1][1] += x1 * wv.y; acc[1][2] += x1 * wv.z; acc[1][3] += x1 * wv.w;
      acc[2][0] += x2 * wv.x; acc[2][1] += x2 * wv.y; acc[2][2] += x2 * wv.z; acc[2][3] += x2 * wv.w;
      acc[3][0] += x3 * wv.x; acc[3][1] += x3 * wv.y; acc[3][2] += x3 * wv.z; acc[3][3] += x3 * wv.w;
    }
  }
#pragma unroll
  for (int r = 0; r < 4; ++r) {
    int gn = nb + r0 + r;
    if (gn < N)
      *(float4*)&y[(size_t)gn * H + c0] = make_float4(acc[r][0], acc[r][1], acc[r][2], acc[r][3]);
  }
}

// hout[n] = y[n] + bias + sum_{j in in(n)} y[j];  also per-block BN partials (sum, sumsq).
// One wave per node. csr indices loaded 64-wide coalesced, broadcast via shfl.
// Broadcast loop is WAVE-UNIFORM so every ds_bpermute source lane is active.
__global__ __launch_bounds__(256) void k_agg(const float* __restrict__ y, const float* __restrict__ bias,
                                             const int* __restrict__ row_ptr, const int* __restrict__ csr,
                                             float* __restrict__ hout, float* __restrict__ bn_part, int N) {
  int wid = threadIdx.x >> 6, lane = threadIdx.x & 63;
  int c = lane & 31, ep = lane >> 5;
  float rsum = 0.f, rsq = 0.f;
  float bc = bias[c];
  int stride = gridDim.x * 4;
  for (int n = blockIdx.x * 4 + wid; n < N; n += stride) {
    int beg = row_ptr[n], end = row_ptr[n + 1];
    float acc = 0.f;
    for (int b0 = beg; b0 < end; b0 += 64) {
      int m = end - b0; if (m > 64) m = 64;          // wave-uniform
      int idx = (lane < m) ? csr[b0 + lane] : 0;
      for (int r = 0; r < m; r += 2) {               // uniform trip count
        int s = r + ep;                              // may be == m when m odd, ep==1
        int j = __shfl(idx, (s < m) ? s : 0, 64);    // full-exec shfl, valid src
        float val = y[(size_t)j * H + c];
        if (s < m) acc += val;                       // predicated accumulate
      }
    }
    acc += __shfl_xor(acc, 32, 64);
    float v = acc + y[(size_t)n * H + c] + bc;
    if (ep == 0) {
      hout[(size_t)n * H + c] = v;
      rsum += v; rsq += v * v;
    }
  }
  __shared__ float bsum[4][H], bsq[4][H];
  if (ep == 0) { bsum[wid][c] = rsum; bsq[wid][c] = rsq; }
  __syncthreads();
  if (threadIdx.x < H) {
    int cc = threadIdx.x;
    bn_part[(size_t)blockIdx.x * 64 + cc]     = bsum[0][cc] + bsum[1][cc] + bsum[2][cc] + bsum[3][cc];
    bn_part[(size_t)blockIdx.x * 64 + H + cc] = bsq[0][cc] + bsq[1][cc] + bsq[2][cc] + bsq[3][cc];
  }
}

// Stage A: 64 blocks, block b reduces rows [32b, 32b+32) of part[2048][64] -> part2[b][64].
__global__ __launch_bounds__(256) void k_bnred(const float* __restrict__ part,
                                               float* __restrict__ part2) {
  int t = threadIdx.x, b = blockIdx.x;
  int col = t & 63, q = t >> 6;                       // 4 row-groups x 8 rows
  int rpb = AGG_BLOCKS / BNRED_NB;                    // 32
  int r0 = b * rpb + q * (rpb / 4);
  float s = 0.f;
  for (int r = r0; r < r0 + rpb / 4; ++r) s += part[(size_t)r * 64 + col];
  __shared__ float red[4][64];
  red[q][col] = s;
  __syncthreads();
  if (t < 64) part2[(size_t)b * 64 + t] = red[0][t] + red[1][t] + red[2][t] + red[3][t];
}

// Stage B: 1 block reduces part[nblk][64] (nblk=64 now) -> scale/shift.
__global__ __launch_bounds__(256) void k_bnfin(const float* __restrict__ part, int nblk,
                                               const float* __restrict__ gma, const float* __restrict__ bet,
                                               float* __restrict__ sc, float invN) {
  int t = threadIdx.x;
  int col = t & 63, q = t >> 6;   // 4 slices
  int per = nblk >> 2;
  float s = 0.f;
  for (int r = q * per; r < (q + 1) * per; ++r) s += part[(size_t)r * 64 + col];
  __shared__ float red[4][64];
  __shared__ float tot[64];
  red[q][col] = s;
  __syncthreads();
  if (t < 64) tot[t] = red[0][t] + red[1][t] + red[2][t] + red[3][t];
  __syncthreads();
  if (t < H) {
    float mean = tot[t] * invN;
    float var = tot[H + t] * invN - mean * mean;
    float scale = gma[t] * rsqrtf(var + 1e-5f);
    sc[t] = scale;
    sc[H + t] = bet[t] - mean * scale;
  }
}

// y2 = relu(relu(BN1(h1)) @ W2 + b2) @ W3 ; thread per node, W in LDS (uniform broadcast reads).
__global__ __launch_bounds__(256) void k_mlp1(const float* __restrict__ h1, const float* __restrict__ sc,
                                              const float* __restrict__ W2, const float* __restrict__ b2,
                                              const float* __restrict__ W3, float* __restrict__ y2, int N) {
  __shared__ __align__(16) float ws2[H * H], ws3[H * H];
  __shared__ float scale_s[H], shift_s[H], b2s[H];
  int t = threadIdx.x;
  for (int i = t; i < H * H; i += 256) { ws2[i] = W2[i]; ws3[i] = W3[i]; }
  if (t < H) { scale_s[t] = sc[t]; shift_s[t] = sc[H + t]; b2s[t] = b2[t]; }
  __syncthreads();
  int n = blockIdx.x * 256 + t;
  if (n >= N) return;
  float a[H], u[H], o[H];
  const float4* hin = (const float4*)&h1[(size_t)n * H];
#pragma unroll
  for (int q = 0; q < H / 4; ++q) {
    float4 v = hin[q];
    a[q * 4 + 0] = fmaxf(v.x * scale_s[q * 4 + 0] + shift_s[q * 4 + 0], 0.f);
    a[q * 4 + 1] = fmaxf(v.y * scale_s[q * 4 + 1] + shift_s[q * 4 + 1], 0.f);
    a[q * 4 + 2] = fmaxf(v.z * scale_s[q * 4 + 2] + shift_s[q * 4 + 2], 0.f);
    a[q * 4 + 3] = fmaxf(v.w * scale_s[q * 4 + 3] + shift_s[q * 4 + 3], 0.f);
  }
#pragma unroll
  for (int c = 0; c < H; ++c) u[c] = b2s[c];
#pragma unroll
  for (int k = 0; k < H; ++k) {
    float av = a[k];
    const float4* wr = (const float4*)&ws2[k * H];
#pragma unroll
    for (int q = 0; q < H / 4; ++q) {
      float4 wv = wr[q];
      u[q * 4 + 0] += av * wv.x; u[q * 4 + 1] += av * wv.y;
      u[q * 4 + 2] += av * wv.z; u[q * 4 + 3] += av * wv.w;
    }
  }
#pragma unroll
  for (int c = 0; c < H; ++c) { u[c] = fmaxf(u[c], 0.f); o[c] = 0.f; }
#pragma unroll
  for (int k = 0; k < H; ++k) {
    float av = u[k];
    const float4* wr = (const float4*)&ws3[k * H];
#pragma unroll
    for (int q = 0; q < H / 4; ++q) {
      float4 wv = wr[q];
      o[q * 4 + 0] += av * wv.x; o[q * 4 + 1] += av * wv.y;
      o[q * 4 + 2] += av * wv.z; o[q * 4 + 3] += av * wv.w;
    }
  }
  float4* yo = (float4*)&y2[(size_t)n * H];
#pragma unroll
  for (int q = 0; q < H / 4; ++q)
    yo[q] = make_float4(o[q * 4 + 0], o[q * 4 + 1], o[q * 4 + 2], o[q * 4 + 3]);
}

// h2 = relu(BN2(h2pre)) @ W4 + b4   (no trailing relu)
__global__ __launch_bounds__(256) void k_mlp2(const float* __restrict__ hpre, const float* __restrict__ sc,
                                              const float* __restrict__ W4, const float* __restrict__ b4,
                                              float* __restrict__ h2, int N) {
  __shared__ __align__(16) float ws4[H * H];
  __shared__ float scale_s[H], shift_s[H], b4s[H];
  int t = threadIdx.x;
  for (int i = t; i < H * H; i += 256) ws4[i] = W4[i];
  if (t < H) { scale_s[t] = sc[t]; shift_s[t] = sc[H + t]; b4s[t] = b4[t]; }
  __syncthreads();
  int n = blockIdx.x * 256 + t;
  if (n >= N) return;
  float a[H], o[H];
  const float4* hin = (const float4*)&hpre[(size_t)n * H];
#pragma unroll
  for (int q = 0; q < H / 4; ++q) {
    float4 v = hin[q];
    a[q * 4 + 0] = fmaxf(v.x * scale_s[q * 4 + 0] + shift_s[q * 4 + 0], 0.f);
    a[q * 4 + 1] = fmaxf(v.y * scale_s[q * 4 + 1] + shift_s[q * 4 + 1], 0.f);
    a[q * 4 + 2] = fmaxf(v.z * scale_s[q * 4 + 2] + shift_s[q * 4 + 2], 0.f);
    a[q * 4 + 3] = fmaxf(v.w * scale_s[q * 4 + 3] + shift_s[q * 4 + 3], 0.f);
  }
#pragma unroll
  for (int c = 0; c < H; ++c) o[c] = b4s[c];
#pragma unroll
  for (int k = 0; k < H; ++k) {
    float av = a[k];
    const float4* wr = (const float4*)&ws4[k * H];
#pragma unroll
    for (int q = 0; q < H / 4; ++q) {
      float4 wv = wr[q];
      o[q * 4 + 0] += av * wv.x; o[q * 4 + 1] += av * wv.y;
      o[q * 4 + 2] += av * wv.z; o[q * 4 + 3] += av * wv.w;
    }
  }
  float4* ho = (float4*)&h2[(size_t)n * H];
#pragma unroll
  for (int q = 0; q < H / 4; ++q)
    ho[q] = make_float4(o[q * 4 + 0], o[q * 4 + 1], o[q * 4 + 2], o[q * 4 + 3]);
}

// batch is sorted: graph g owns node range [lb(g), lb(g+1)). Wave per graph, mean||max -> z[G,64].
__global__ __launch_bounds__(256) void k_pool(const float* __restrict__ h2, const int* __restrict__ batch,
                                              int N, int G, float* __restrict__ z) {
  int wid = threadIdx.x >> 6, lane = threadIdx.x & 63;
  int g = blockIdx.x * 4 + wid;
  if (g >= G) return;
  int beg = lower_bound_i(batch, N, g);
  int end = lower_bound_i(batch, N, g + 1);
  int c = lane & 31, ep = lane >> 5;
  float s = 0.f, m = -3.402823466e38f;
  for (int i = beg + ep; i < end; i += 2) {
    float v = h2[(size_t)i * H + c];
    s += v; m = fmaxf(m, v);
  }
  s += __shfl_xor(s, 32, 64);
  m = fmaxf(m, __shfl_xor(m, 32, 64));
  if (ep == 0) {
    int cnt = end - beg;
    z[(size_t)g * 64 + c]     = (cnt > 0) ? s / (float)cnt : 0.f;
    z[(size_t)g * 64 + H + c] = (cnt > 0) ? m : 0.f;
  }
}

// out = relu(z @ Wc1 + bc1) @ Wc2 + bc2 ; thread per graph.
__global__ __launch_bounds__(256) void k_cls(const float* __restrict__ z, const float* __restrict__ Wc1,
                                             const float* __restrict__ bc1, const float* __restrict__ Wc2,
                                             const float* __restrict__ bc2, float* __restrict__ out, int G) {
  __shared__ __align__(16) float w1s[64 * H];
  __shared__ float w2s[H * 2], b1s[H], b2s[2];
  int t = threadIdx.x;
  for (int i = t; i < 64 * H; i += 256) w1s[i] = Wc1[i];
  if (t < H * 2) w2s[t] = Wc2[t];
  if (t < H) b1s[t] = bc1[t];
  if (t < 2) b2s[t] = bc2[t];
  __syncthreads();
  int g = blockIdx.x * 256 + t;
  if (g >= G) return;
  float zr[64], u[H];
  const float4* zp = (const float4*)&z[(size_t)g * 64];
#pragma unroll
  for (int q = 0; q < 16; ++q) {
    float4 v = zp[q];
    zr[q * 4 + 0] = v.x; zr[q * 4 + 1] = v.y; zr[q * 4 + 2] = v.z; zr[q * 4 + 3] = v.w;
  }
#pragma unroll
  for (int c = 0; c < H; ++c) u[c] = b1s[c];
#pragma unroll
  for (int k = 0; k < 64; ++k) {
    float av = zr[k];
    const float4* wr = (const float4*)&w1s[k * H];
#pragma unroll
    for (int q = 0; q < H / 4; ++q) {
      float4 wv = wr[q];
      u[q * 4 + 0] += av * wv.x; u[q * 4 + 1] += av * wv.y;
      u[q * 4 + 2] += av * wv.z; u[q * 4 + 3] += av * wv.w;
    }
  }
  float o0 = b2s[0], o1 = b2s[1];
#pragma unroll
  for (int k = 0; k < H; ++k) {
    float uv = fmaxf(u[k], 0.f);
    o0 += uv * w2s[k * 2 + 0];
    o1 += uv * w2s[k * 2 + 1];
  }
  out[(size_t)g * 2 + 0] = o0;
  out[(size_t)g * 2 + 1] = o1;
}

extern "C" void kernel_launch(void* const* d_in, const int* in_sizes, int n_in,
                              void* d_out, int out_size, void* d_ws, size_t ws_size,
                              hipStream_t stream) {
  const float* x    = (const float*)d_in[0];
  const int*   eidx = (const int*)d_in[1];
  const int*   batch= (const int*)d_in[2];
  const float* W1 = (const float*)d_in[3];
  const float* b1 = (const float*)d_in[4];
  const float* g1 = (const float*)d_in[5];
  const float* be1= (const float*)d_in[6];
  const float* W2 = (const float*)d_in[7];
  const float* b2 = (const float*)d_in[8];
  const float* W3 = (const float*)d_in[9];
  const float* b3 = (const float*)d_in[10];
  const float* g2 = (const float*)d_in[11];
  const float* be2= (const float*)d_in[12];
  const float* W4 = (const float*)d_in[13];
  const float* b4 = (const float*)d_in[14];
  const float* Wc1= (const float*)d_in[15];
  const float* bc1= (const float*)d_in[16];
  const float* Wc2= (const float*)d_in[17];
  const float* bc2= (const float*)d_in[18];
  (void)n_in; (void)ws_size;

  int N = in_sizes[2];       // 100000
  int E = in_sizes[1] / 2;   // 1600000
  int G = out_size / 2;      // 1000
  int nbuck = (N + BKT_SZ - 1) >> BKT_SHIFT;   // 196
  const int* srcv = eidx;
  const int* dstv = eidx + E;

  char* w = (char*)d_ws;
  auto carve = [&](size_t bytes) { void* p = (void*)w; w += (bytes + 255) & ~(size_t)255; return p; };
  float*    bufA    = (float*)carve((size_t)N * H * 4);      // y1 -> y2 -> h2
  float*    bufB    = (float*)carve((size_t)N * H * 4);      // h1 -> h2pre
  int*      row_ptr = (int*)carve((size_t)(N + 1) * 4);
  int*      csr     = (int*)carve((size_t)E * 4);
  unsigned* staging = (unsigned*)carve((size_t)E * 4);
  int*      gbcnt   = (int*)carve(256 * 4);
  int*      bbase   = (int*)carve(257 * 4);
  int*      bcur    = (int*)carve(256 * 4);
  float*    bnp     = (float*)carve((size_t)AGG_BLOCKS * 64 * 4);
  float*    bnp2    = (float*)carve((size_t)BNRED_NB * 64 * 4);
  float*    sc1     = (float*)carve(64 * 4);
  float*    sc2     = (float*)carve(64 * 4);
  float*    z       = (float*)carve((size_t)G * 64 * 4);

  int abk = (E + ACHUNK - 1) / ACHUNK;   // 391

  hipMemsetAsync(gbcnt, 0, 256 * 4, stream);
  k_bhist<<<abk, 256, 0, stream>>>(dstv, E, gbcnt);
  k_bscan<<<1, 256, 0, stream>>>(gbcnt, nbuck, bbase, bcur);
  k_bucketA<<<abk, 256, 0, stream>>>(srcv, dstv, E, bcur, staging);
  k_bucketB<<<nbuck, 256, 0, stream>>>(staging, bbase, N, row_ptr, csr);
  k_gemm1<<<(N + 127) / 128, 256, 0, stream>>>(x, W1, bufA, N);
  k_agg<<<AGG_BLOCKS, 256, 0, stream>>>(bufA, b1, row_ptr, csr, bufB, bnp, N);
  k_bnred<<<BNRED_NB, 256, 0, stream>>>(bnp, bnp2);
  k_bnfin<<<1, 256, 0, stream>>>(bnp2, BNRED_NB, g1, be1, sc1, 1.0f / (float)N);
  k_mlp1<<<(N + 255) / 256, 256, 0, stream>>>(bufB, sc1, W2, b2, W3, bufA, N);
  k_agg<<<AGG_BLOCKS, 256, 0, stream>>>(bufA, b3, row_ptr, csr, bufB, bnp, N);
  k_bnred<<<BNRED_NB, 256, 0, stream>>>(bnp, bnp2);
  k_bnfin<<<1, 256, 0, stream>>>(bnp2, BNRED_NB, g2, be2, sc2, 1.0f / (float)N);
  k_mlp2<<<(N + 255) / 256, 256, 0, stream>>>(bufB, sc2, W4, b4, bufA, N);
  k_pool<<<(G + 3) / 4, 256, 0, stream>>>(bufA, batch, N, G, z);
  k_cls<<<(G + 255) / 256, 256, 0, stream>>>(z, Wc1, bc1, Wc2, bc2, (float*)d_out, G);
}

// Round 8
// 388.819 us; speedup vs baseline: 2.8202x; 1.1148x over previous
//
#include <hip/hip_runtime.h>

// GIN-2layer + pool + classifier for MI355X.
// R7 change (measured: k_agg 64us x2, VALUBusy 25%, 1.56TB/s = latency-bound,
// ~1 outstanding gather/wave because acc+=val forces vmcnt wait per iter):
//   k_agg gather loop 4-deep unrolled -> 4 independent row gathers in flight
//   per wave before the first waitcnt (MLP x4). All shfl remain at full
//   convergence (uniform bounds; unrolled body proves s+6+ep < m).
// Kept: counting-sort CSR (R6), hierarchical BN reduce (R5), R4 shfl fix.

#define H 32
#define FIN 128
#define AGG_BLOCKS 2048
#define BNRED_NB 64

#define BKT_SHIFT 9
#define BKT_SZ 512          // nodes per bucket; nbuck = ceil(N/512) = 196 <= 256
#define ACHUNK 4096         // edges per block in bhist/bucketA

__device__ __forceinline__ int lower_bound_i(const int* __restrict__ a, int n, int key) {
  int lo = 0, hi = n;
  while (lo < hi) { int mid = (lo + hi) >> 1; if (a[mid] < key) lo = mid + 1; else hi = mid; }
  return lo;
}

// ---- CSR build: two-level counting sort ----

__global__ __launch_bounds__(256) void k_bhist(const int* __restrict__ dst, int E,
                                               int* __restrict__ gbcnt) {
  __shared__ int cnt[256];
  int t = threadIdx.x;
  int e0 = blockIdx.x * ACHUNK, e1 = min(e0 + ACHUNK, E);
  cnt[t] = 0;
  __syncthreads();
  for (int i = e0 + t; i < e1; i += 256) atomicAdd(&cnt[dst[i] >> BKT_SHIFT], 1);
  __syncthreads();
  if (cnt[t] > 0) atomicAdd(&gbcnt[t], cnt[t]);
}

__global__ __launch_bounds__(256) void k_bscan(const int* __restrict__ gbcnt, int nbuck,
                                               int* __restrict__ bbase, int* __restrict__ bcur) {
  int t = threadIdx.x;
  __shared__ int sh[256];
  int v0 = (t < nbuck) ? gbcnt[t] : 0;
  sh[t] = v0;
  __syncthreads();
  for (int d = 1; d < 256; d <<= 1) {
    int v = (t >= d) ? sh[t - d] : 0;
    __syncthreads();
    sh[t] += v;
    __syncthreads();
  }
  int excl = sh[t] - v0;
  if (t < nbuck) { bbase[t] = excl; bcur[t] = excl; }
  if (t == 255) bbase[nbuck] = sh[255];
}

__global__ __launch_bounds__(256) void k_bucketA(const int* __restrict__ src, const int* __restrict__ dst,
                                                 int E, int* __restrict__ bcur,
                                                 unsigned* __restrict__ staging) {
  __shared__ int cnt[256];
  __shared__ int base[256];
  int t = threadIdx.x;
  int e0 = blockIdx.x * ACHUNK, e1 = min(e0 + ACHUNK, E);
  cnt[t] = 0;
  __syncthreads();
  for (int i = e0 + t; i < e1; i += 256) atomicAdd(&cnt[dst[i] >> BKT_SHIFT], 1);
  __syncthreads();
  int c = cnt[t];
  base[t] = (c > 0) ? atomicAdd(&bcur[t], c) : 0;
  __syncthreads();
  for (int i = e0 + t; i < e1; i += 256) {
    int d = dst[i];
    int p = atomicAdd(&base[d >> BKT_SHIFT], 1);
    staging[p] = ((unsigned)(d & (BKT_SZ - 1)) << 17) | (unsigned)src[i];
  }
}

// One block per bucket: per-node hist (512) + scan -> row_ptr slice + sorted csr.
__global__ __launch_bounds__(256) void k_bucketB(const unsigned* __restrict__ staging,
                                                 const int* __restrict__ bbase, int N,
                                                 int* __restrict__ row_ptr, int* __restrict__ csr) {
  __shared__ int cnt[BKT_SZ];
  __shared__ int ptr[BKT_SZ];
  __shared__ int sc[256];
  int t = threadIdx.x, b = blockIdx.x;
  int nb0 = b << BKT_SHIFT;
  int nb1 = min(nb0 + BKT_SZ, N);
  int seg0 = bbase[b];
  int len = bbase[b + 1] - seg0;
  cnt[t] = 0; cnt[t + 256] = 0;
  __syncthreads();
  for (int i = t; i < len; i += 256) atomicAdd(&cnt[staging[seg0 + i] >> 17], 1);
  __syncthreads();
  int s2 = cnt[2 * t] + cnt[2 * t + 1];
  sc[t] = s2;
  __syncthreads();
  for (int d = 1; d < 256; d <<= 1) {
    int v = (t >= d) ? sc[t - d] : 0;
    __syncthreads();
    sc[t] += v;
    __syncthreads();
  }
  int base0 = sc[t] - s2;
  ptr[2 * t] = base0;
  ptr[2 * t + 1] = base0 + cnt[2 * t];
  __syncthreads();
  int nn = nb1 - nb0;
  if (2 * t < nn)     row_ptr[nb0 + 2 * t]     = seg0 + ptr[2 * t];
  if (2 * t + 1 < nn) row_ptr[nb0 + 2 * t + 1] = seg0 + ptr[2 * t + 1];
  if (t == 0 && nb1 == N) row_ptr[N] = seg0 + len;
  __syncthreads();
  for (int i = t; i < len; i += 256) {
    unsigned e = staging[seg0 + i];
    int d = (int)(e >> 17);
    int k = atomicAdd(&ptr[d], 1);
    csr[seg0 + k] = (int)(e & 0x1FFFFu);
  }
}

// ---- main pipeline kernels ----

// y[N,32] = x[N,128] @ W[128,32].  128 nodes/block, thread tile 4 nodes x 4 cols.
__global__ __launch_bounds__(256) void k_gemm1(const float* __restrict__ x, const float* __restrict__ W,
                                               float* __restrict__ y, int N) {
  __shared__ __align__(16) float ws[FIN * H];   // 16 KB, [k][c]
  __shared__ __align__(16) float xs[128 * 33];  // k-chunk of 32 (+1 pad)
  int t = threadIdx.x;
  for (int i = t; i < FIN * H; i += 256) ws[i] = W[i];
  int nb = blockIdx.x * 128;
  int r0 = (t >> 3) * 4;   // 0..124
  int c0 = (t & 7) * 4;    // 0..28
  float acc[4][4] = {{0.f,0.f,0.f,0.f},{0.f,0.f,0.f,0.f},{0.f,0.f,0.f,0.f},{0.f,0.f,0.f,0.f}};
  for (int kb = 0; kb < FIN; kb += 32) {
    __syncthreads();
    for (int i = t; i < 1024; i += 256) {  // 1024 float4 = [128][32] chunk
      int n = i >> 3, k4 = (i & 7) * 4;
      float4 v = make_float4(0.f, 0.f, 0.f, 0.f);
      int gn = nb + n;
      if (gn < N) v = *(const float4*)&x[(size_t)gn * FIN + kb + k4];
      xs[n * 33 + k4 + 0] = v.x; xs[n * 33 + k4 + 1] = v.y;
      xs[n * 33 + k4 + 2] = v.z; xs[n * 33 + k4 + 3] = v.w;
    }
    __syncthreads();
#pragma unroll
    for (int k = 0; k < 32; ++k) {
      float4 wv = *(const float4*)&ws[(kb + k) * H + c0];
      float x0 = xs[(r0 + 0) * 33 + k];
      float x1 = xs[(r0 + 1) * 33 + k];
      float x2 = xs[(r0 + 2) * 33 + k];
      float x3 = xs[(r0 + 3) * 33 + k];
      acc[0][0] += x0 * wv.x; acc[0][1] += x0 * wv.y; acc[0][2] += x0 * wv.z; acc[0][3] += x0 * wv.w;
      acc[1][0] += x1 * wv.x; acc[1][1] += x1 * wv.y; acc[1][2] += x1 * wv.z; acc[1][3] += x1 * wv.w;
      acc[2][0] += x2 * wv.x; acc[2][1] += x2 * wv.y; acc[2][2] += x2 * wv.z; acc[2][3] += x2 * wv.w;
      acc[3][0] += x3 * wv.x; acc[3][1] += x3 * wv.y; acc[3][2] += x3 * wv.z; acc[3][3] += x3 * wv.w;
    }
  }
#pragma unroll
  for (int r = 0; r < 4; ++r) {
    int gn = nb + r0 + r;
    if (gn < N)
      *(float4*)&y[(size_t)gn * H + c0] = make_float4(acc[r][0], acc[r][1], acc[r][2], acc[r][3]);
  }
}

// hout[n] = y[n] + bias + sum_{j in in(n)} y[j];  also per-block BN partials.
// One wave per node, lane = 2-edge x 32-channel. Gather loop 4-deep unrolled:
// 4 independent row gathers in flight per wave before the first vmcnt wait.
// All shfl at full convergence: loop bounds wave-uniform; body has s+ep < m.
__global__ __launch_bounds__(256) void k_agg(const float* __restrict__ y, const float* __restrict__ bias,
                                             const int* __restrict__ row_ptr, const int* __restrict__ csr,
                                             float* __restrict__ hout, float* __restrict__ bn_part, int N) {
  int wid = threadIdx.x >> 6, lane = threadIdx.x & 63;
  int c = lane & 31, ep = lane >> 5;
  float rsum = 0.f, rsq = 0.f;
  float bc = bias[c];
  int stride = gridDim.x * 4;
  for (int n = blockIdx.x * 4 + wid; n < N; n += stride) {
    int beg = row_ptr[n], end = row_ptr[n + 1];
    float acc = 0.f;
    for (int b0 = beg; b0 < end; b0 += 64) {
      int m = end - b0; if (m > 64) m = 64;          // wave-uniform
      int idx = (lane < m) ? csr[b0 + lane] : 0;
      int r = 0;
      for (; r + 8 <= m; r += 8) {                   // unrolled: s = r+2q+ep <= m-2+1 < m
        int j0 = __shfl(idx, r + 0 + ep, 64);
        int j1 = __shfl(idx, r + 2 + ep, 64);
        int j2 = __shfl(idx, r + 4 + ep, 64);
        int j3 = __shfl(idx, r + 6 + ep, 64);
        float v0 = y[(size_t)j0 * H + c];
        float v1 = y[(size_t)j1 * H + c];
        float v2 = y[(size_t)j2 * H + c];
        float v3 = y[(size_t)j3 * H + c];
        acc += (v0 + v1) + (v2 + v3);
      }
      for (; r < m; r += 2) {                        // wave-uniform tail
        int s = r + ep;                              // may be == m when m odd, ep==1
        int j = __shfl(idx, (s < m) ? s : 0, 64);    // full-exec shfl, valid src
        float val = y[(size_t)j * H + c];
        if (s < m) acc += val;                       // predicated accumulate
      }
    }
    acc += __shfl_xor(acc, 32, 64);
    float v = acc + y[(size_t)n * H + c] + bc;
    if (ep == 0) {
      hout[(size_t)n * H + c] = v;
      rsum += v; rsq += v * v;
    }
  }
  __shared__ float bsum[4][H], bsq[4][H];
  if (ep == 0) { bsum[wid][c] = rsum; bsq[wid][c] = rsq; }
  __syncthreads();
  if (threadIdx.x < H) {
    int cc = threadIdx.x;
    bn_part[(size_t)blockIdx.x * 64 + cc]     = bsum[0][cc] + bsum[1][cc] + bsum[2][cc] + bsum[3][cc];
    bn_part[(size_t)blockIdx.x * 64 + H + cc] = bsq[0][cc] + bsq[1][cc] + bsq[2][cc] + bsq[3][cc];
  }
}

// Stage A: 64 blocks, block b reduces rows [32b, 32b+32) of part[2048][64] -> part2[b][64].
__global__ __launch_bounds__(256) void k_bnred(const float* __restrict__ part,
                                               float* __restrict__ part2) {
  int t = threadIdx.x, b = blockIdx.x;
  int col = t & 63, q = t >> 6;                       // 4 row-groups x 8 rows
  int rpb = AGG_BLOCKS / BNRED_NB;                    // 32
  int r0 = b * rpb + q * (rpb / 4);
  float s = 0.f;
  for (int r = r0; r < r0 + rpb / 4; ++r) s += part[(size_t)r * 64 + col];
  __shared__ float red[4][64];
  red[q][col] = s;
  __syncthreads();
  if (t < 64) part2[(size_t)b * 64 + t] = red[0][t] + red[1][t] + red[2][t] + red[3][t];
}

// Stage B: 1 block reduces part[nblk][64] (nblk=64 now) -> scale/shift.
__global__ __launch_bounds__(256) void k_bnfin(const float* __restrict__ part, int nblk,
                                               const float* __restrict__ gma, const float* __restrict__ bet,
                                               float* __restrict__ sc, float invN) {
  int t = threadIdx.x;
  int col = t & 63, q = t >> 6;   // 4 slices
  int per = nblk >> 2;
  float s = 0.f;
  for (int r = q * per; r < (q + 1) * per; ++r) s += part[(size_t)r * 64 + col];
  __shared__ float red[4][64];
  __shared__ float tot[64];
  red[q][col] = s;
  __syncthreads();
  if (t < 64) tot[t] = red[0][t] + red[1][t] + red[2][t] + red[3][t];
  __syncthreads();
  if (t < H) {
    float mean = tot[t] * invN;
    float var = tot[H + t] * invN - mean * mean;
    float scale = gma[t] * rsqrtf(var + 1e-5f);
    sc[t] = scale;
    sc[H + t] = bet[t] - mean * scale;
  }
}

// y2 = relu(relu(BN1(h1)) @ W2 + b2) @ W3 ; thread per node, W in LDS (uniform broadcast reads).
__global__ __launch_bounds__(256) void k_mlp1(const float* __restrict__ h1, const float* __restrict__ sc,
                                              const float* __restrict__ W2, const float* __restrict__ b2,
                                              const float* __restrict__ W3, float* __restrict__ y2, int N) {
  __shared__ __align__(16) float ws2[H * H], ws3[H * H];
  __shared__ float scale_s[H], shift_s[H], b2s[H];
  int t = threadIdx.x;
  for (int i = t; i < H * H; i += 256) { ws2[i] = W2[i]; ws3[i] = W3[i]; }
  if (t < H) { scale_s[t] = sc[t]; shift_s[t] = sc[H + t]; b2s[t] = b2[t]; }
  __syncthreads();
  int n = blockIdx.x * 256 + t;
  if (n >= N) return;
  float a[H], u[H], o[H];
  const float4* hin = (const float4*)&h1[(size_t)n * H];
#pragma unroll
  for (int q = 0; q < H / 4; ++q) {
    float4 v = hin[q];
    a[q * 4 + 0] = fmaxf(v.x * scale_s[q * 4 + 0] + shift_s[q * 4 + 0], 0.f);
    a[q * 4 + 1] = fmaxf(v.y * scale_s[q * 4 + 1] + shift_s[q * 4 + 1], 0.f);
    a[q * 4 + 2] = fmaxf(v.z * scale_s[q * 4 + 2] + shift_s[q * 4 + 2], 0.f);
    a[q * 4 + 3] = fmaxf(v.w * scale_s[q * 4 + 3] + shift_s[q * 4 + 3], 0.f);
  }
#pragma unroll
  for (int c = 0; c < H; ++c) u[c] = b2s[c];
#pragma unroll
  for (int k = 0; k < H; ++k) {
    float av = a[k];
    const float4* wr = (const float4*)&ws2[k * H];
#pragma unroll
    for (int q = 0; q < H / 4; ++q) {
      float4 wv = wr[q];
      u[q * 4 + 0] += av * wv.x; u[q * 4 + 1] += av * wv.y;
      u[q * 4 + 2] += av * wv.z; u[q * 4 + 3] += av * wv.w;
    }
  }
#pragma unroll
  for (int c = 0; c < H; ++c) { u[c] = fmaxf(u[c], 0.f); o[c] = 0.f; }
#pragma unroll
  for (int k = 0; k < H; ++k) {
    float av = u[k];
    const float4* wr = (const float4*)&ws3[k * H];
#pragma unroll
    for (int q = 0; q < H / 4; ++q) {
      float4 wv = wr[q];
      o[q * 4 + 0] += av * wv.x; o[q * 4 + 1] += av * wv.y;
      o[q * 4 + 2] += av * wv.z; o[q * 4 + 3] += av * wv.w;
    }
  }
  float4* yo = (float4*)&y2[(size_t)n * H];
#pragma unroll
  for (int q = 0; q < H / 4; ++q)
    yo[q] = make_float4(o[q * 4 + 0], o[q * 4 + 1], o[q * 4 + 2], o[q * 4 + 3]);
}

// h2 = relu(BN2(h2pre)) @ W4 + b4   (no trailing relu)
__global__ __launch_bounds__(256) void k_mlp2(const float* __restrict__ hpre, const float* __restrict__ sc,
                                              const float* __restrict__ W4, const float* __restrict__ b4,
                                              float* __restrict__ h2, int N) {
  __shared__ __align__(16) float ws4[H * H];
  __shared__ float scale_s[H], shift_s[H], b4s[H];
  int t = threadIdx.x;
  for (int i = t; i < H * H; i += 256) ws4[i] = W4[i];
  if (t < H) { scale_s[t] = sc[t]; shift_s[t] = sc[H + t]; b4s[t] = b4[t]; }
  __syncthreads();
  int n = blockIdx.x * 256 + t;
  if (n >= N) return;
  float a[H], o[H];
  const float4* hin = (const float4*)&hpre[(size_t)n * H];
#pragma unroll
  for (int q = 0; q < H / 4; ++q) {
    float4 v = hin[q];
    a[q * 4 + 0] = fmaxf(v.x * scale_s[q * 4 + 0] + shift_s[q * 4 + 0], 0.f);
    a[q * 4 + 1] = fmaxf(v.y * scale_s[q * 4 + 1] + shift_s[q * 4 + 1], 0.f);
    a[q * 4 + 2] = fmaxf(v.z * scale_s[q * 4 + 2] + shift_s[q * 4 + 2], 0.f);
    a[q * 4 + 3] = fmaxf(v.w * scale_s[q * 4 + 3] + shift_s[q * 4 + 3], 0.f);
  }
#pragma unroll
  for (int c = 0; c < H; ++c) o[c] = b4s[c];
#pragma unroll
  for (int k = 0; k < H; ++k) {
    float av = a[k];
    const float4* wr = (const float4*)&ws4[k * H];
#pragma unroll
    for (int q = 0; q < H / 4; ++q) {
      float4 wv = wr[q];
      o[q * 4 + 0] += av * wv.x; o[q * 4 + 1] += av * wv.y;
      o[q * 4 + 2] += av * wv.z; o[q * 4 + 3] += av * wv.w;
    }
  }
  float4* ho = (float4*)&h2[(size_t)n * H];
#pragma unroll
  for (int q = 0; q < H / 4; ++q)
    ho[q] = make_float4(o[q * 4 + 0], o[q * 4 + 1], o[q * 4 + 2], o[q * 4 + 3]);
}

// batch is sorted: graph g owns node range [lb(g), lb(g+1)). Wave per graph, mean||max -> z[G,64].
__global__ __launch_bounds__(256) void k_pool(const float* __restrict__ h2, const int* __restrict__ batch,
                                              int N, int G, float* __restrict__ z) {
  int wid = threadIdx.x >> 6, lane = threadIdx.x & 63;
  int g = blockIdx.x * 4 + wid;
  if (g >= G) return;
  int beg = lower_bound_i(batch, N, g);
  int end = lower_bound_i(batch, N, g + 1);
  int c = lane & 31, ep = lane >> 5;
  float s = 0.f, m = -3.402823466e38f;
  for (int i = beg + ep; i < end; i += 2) {
    float v = h2[(size_t)i * H + c];
    s += v; m = fmaxf(m, v);
  }
  s += __shfl_xor(s, 32, 64);
  m = fmaxf(m, __shfl_xor(m, 32, 64));
  if (ep == 0) {
    int cnt = end - beg;
    z[(size_t)g * 64 + c]     = (cnt > 0) ? s / (float)cnt : 0.f;
    z[(size_t)g * 64 + H + c] = (cnt > 0) ? m : 0.f;
  }
}

// out = relu(z @ Wc1 + bc1) @ Wc2 + bc2 ; thread per graph.
__global__ __launch_bounds__(256) void k_cls(const float* __restrict__ z, const float* __restrict__ Wc1,
                                             const float* __restrict__ bc1, const float* __restrict__ Wc2,
                                             const float* __restrict__ bc2, float* __restrict__ out, int G) {
  __shared__ __align__(16) float w1s[64 * H];
  __shared__ float w2s[H * 2], b1s[H], b2s[2];
  int t = threadIdx.x;
  for (int i = t; i < 64 * H; i += 256) w1s[i] = Wc1[i];
  if (t < H * 2) w2s[t] = Wc2[t];
  if (t < H) b1s[t] = bc1[t];
  if (t < 2) b2s[t] = bc2[t];
  __syncthreads();
  int g = blockIdx.x * 256 + t;
  if (g >= G) return;
  float zr[64], u[H];
  const float4* zp = (const float4*)&z[(size_t)g * 64];
#pragma unroll
  for (int q = 0; q < 16; ++q) {
    float4 v = zp[q];
    zr[q * 4 + 0] = v.x; zr[q * 4 + 1] = v.y; zr[q * 4 + 2] = v.z; zr[q * 4 + 3] = v.w;
  }
#pragma unroll
  for (int c = 0; c < H; ++c) u[c] = b1s[c];
#pragma unroll
  for (int k = 0; k < 64; ++k) {
    float av = zr[k];
    const float4* wr = (const float4*)&w1s[k * H];
#pragma unroll
    for (int q = 0; q < H / 4; ++q) {
      float4 wv = wr[q];
      u[q * 4 + 0] += av * wv.x; u[q * 4 + 1] += av * wv.y;
      u[q * 4 + 2] += av * wv.z; u[q * 4 + 3] += av * wv.w;
    }
  }
  float o0 = b2s[0], o1 = b2s[1];
#pragma unroll
  for (int k = 0; k < H; ++k) {
    float uv = fmaxf(u[k], 0.f);
    o0 += uv * w2s[k * 2 + 0];
    o1 += uv * w2s[k * 2 + 1];
  }
  out[(size_t)g * 2 + 0] = o0;
  out[(size_t)g * 2 + 1] = o1;
}

extern "C" void kernel_launch(void* const* d_in, const int* in_sizes, int n_in,
                              void* d_out, int out_size, void* d_ws, size_t ws_size,
                              hipStream_t stream) {
  const float* x    = (const float*)d_in[0];
  const int*   eidx = (const int*)d_in[1];
  const int*   batch= (const int*)d_in[2];
  const float* W1 = (const float*)d_in[3];
  const float* b1 = (const float*)d_in[4];
  const float* g1 = (const float*)d_in[5];
  const float* be1= (const float*)d_in[6];
  const float* W2 = (const float*)d_in[7];
  const float* b2 = (const float*)d_in[8];
  const float* W3 = (const float*)d_in[9];
  const float* b3 = (const float*)d_in[10];
  const float* g2 = (const float*)d_in[11];
  const float* be2= (const float*)d_in[12];
  const float* W4 = (const float*)d_in[13];
  const float* b4 = (const float*)d_in[14];
  const float* Wc1= (const float*)d_in[15];
  const float* bc1= (const float*)d_in[16];
  const float* Wc2= (const float*)d_in[17];
  const float* bc2= (const float*)d_in[18];
  (void)n_in; (void)ws_size;

  int N = in_sizes[2];       // 100000
  int E = in_sizes[1] / 2;   // 1600000
  int G = out_size / 2;      // 1000
  int nbuck = (N + BKT_SZ - 1) >> BKT_SHIFT;   // 196
  const int* srcv = eidx;
  const int* dstv = eidx + E;

  char* w = (char*)d_ws;
  auto carve = [&](size_t bytes) { void* p = (void*)w; w += (bytes + 255) & ~(size_t)255; return p; };
  float*    bufA    = (float*)carve((size_t)N * H * 4);      // y1 -> y2 -> h2
  float*    bufB    = (float*)carve((size_t)N * H * 4);      // h1 -> h2pre
  int*      row_ptr = (int*)carve((size_t)(N + 1) * 4);
  int*      csr     = (int*)carve((size_t)E * 4);
  unsigned* staging = (unsigned*)carve((size_t)E * 4);
  int*      gbcnt   = (int*)carve(256 * 4);
  int*      bbase   = (int*)carve(257 * 4);
  int*      bcur    = (int*)carve(256 * 4);
  float*    bnp     = (float*)carve((size_t)AGG_BLOCKS * 64 * 4);
  float*    bnp2    = (float*)carve((size_t)BNRED_NB * 64 * 4);
  float*    sc1     = (float*)carve(64 * 4);
  float*    sc2     = (float*)carve(64 * 4);
  float*    z       = (float*)carve((size_t)G * 64 * 4);

  int abk = (E + ACHUNK - 1) / ACHUNK;   // 391

  hipMemsetAsync(gbcnt, 0, 256 * 4, stream);
  k_bhist<<<abk, 256, 0, stream>>>(dstv, E, gbcnt);
  k_bscan<<<1, 256, 0, stream>>>(gbcnt, nbuck, bbase, bcur);
  k_bucketA<<<abk, 256, 0, stream>>>(srcv, dstv, E, bcur, staging);
  k_bucketB<<<nbuck, 256, 0, stream>>>(staging, bbase, N, row_ptr, csr);
  k_gemm1<<<(N + 127) / 128, 256, 0, stream>>>(x, W1, bufA, N);
  k_agg<<<AGG_BLOCKS, 256, 0, stream>>>(bufA, b1, row_ptr, csr, bufB, bnp, N);
  k_bnred<<<BNRED_NB, 256, 0, stream>>>(bnp, bnp2);
  k_bnfin<<<1, 256, 0, stream>>>(bnp2, BNRED_NB, g1, be1, sc1, 1.0f / (float)N);
  k_mlp1<<<(N + 255) / 256, 256, 0, stream>>>(bufB, sc1, W2, b2, W3, bufA, N);
  k_agg<<<AGG_BLOCKS, 256, 0, stream>>>(bufA, b3, row_ptr, csr, bufB, bnp, N);
  k_bnred<<<BNRED_NB, 256, 0, stream>>>(bnp, bnp2);
  k_bnfin<<<1, 256, 0, stream>>>(bnp2, BNRED_NB, g2, be2, sc2, 1.0f / (float)N);
  k_mlp2<<<(N + 255) / 256, 256, 0, stream>>>(bufB, sc2, W4, b4, bufA, N);
  k_pool<<<(G + 3) / 4, 256, 0, stream>>>(bufA, batch, N, G, z);
  k_cls<<<(G + 255) / 256, 256, 0, stream>>>(z, Wc1, bc1, Wc2, bc2, (float*)d_out, G);
}